// Round 1
// baseline (267.691 us; speedup 1.0000x reference)
//
#include <hip/hip_runtime.h>
#include <hip/hip_bf16.h>

#define DEVFN __device__ __forceinline__

// MFMA fragment types (per cdna_hip_programming.md §3: short vectors match reg counts)
typedef __attribute__((ext_vector_type(8))) short bf16x8;   // 8 bf16 = 4 VGPR
typedef __attribute__((ext_vector_type(4))) short s16x4;    // 4 bf16 = 2 VGPR
typedef __attribute__((ext_vector_type(4))) float f32x4;

constexpr int Bc = 2, Sc = 2048, Dc = 1024, Hc = 16, HDc = 64;
constexpr float SCALEc = 0.125f;  // HD^-0.5

DEVFN unsigned short f2bf(float f) {  // RNE fp32 -> bf16
    union { float f; unsigned int u; } x; x.f = f;
    unsigned int r = (x.u + 0x7fffu + ((x.u >> 16) & 1u)) >> 16;
    return (unsigned short)r;
}

DEVFN f32x4 mfma16x16x32(bf16x8 a, bf16x8 b, f32x4 c) {
    return __builtin_amdgcn_mfma_f32_16x16x32_bf16(a, b, c, 0, 0, 0);
}

// C = A * B^T + bias. A: [4096 x 1024] (fp32 or bf16, row-major), B: [1024 x 1024] fp32
// row-major (i.e. torch Linear weight, N x K). MODE 0: bf16 out, head-permuted
// [B,H,S,HD], scaled. MODE 1: fp32 out, row-major [M,N].
template <bool A_BF16, int MODE>
__global__ __launch_bounds__(256) void gemm_bt(
    const void* __restrict__ Ap, const float* __restrict__ Bw,
    const float* __restrict__ bias, void* __restrict__ Yp, float scale)
{
    constexpr int M = Bc * Sc, N = Dc, K = Dc;
    constexpr int BM = 128, BN = 128, BK = 32, LDT = 40;  // +8 pad: bank spread
    __shared__ short As[BM][LDT];
    __shared__ short Bs[BN][LDT];

    const int tid  = threadIdx.x;
    const int lane = tid & 63, w = tid >> 6;
    const int lr = lane & 15, lg = lane >> 4;
    const int tm = blockIdx.x & (M / BM - 1);   // 32 m-tiles
    const int tn = blockIdx.x >> 5;             // 8 n-tiles
    const int wm = (w >> 1) * 64, wn = (w & 1) * 64;
    const int sr = tid >> 1, sh = (tid & 1) * 16;  // staging: row, 16-col half

    f32x4 acc[4][4];
    #pragma unroll
    for (int m = 0; m < 4; m++)
        #pragma unroll
        for (int n = 0; n < 4; n++) acc[m][n] = (f32x4){0.f, 0.f, 0.f, 0.f};

    for (int k0 = 0; k0 < K; k0 += BK) {
        __syncthreads();
        if constexpr (!A_BF16) {
            const float* A = (const float*)Ap;
            const float4* src = (const float4*)(A + (size_t)(tm * BM + sr) * K + k0 + sh);
            unsigned short tmp[16];
            #pragma unroll
            for (int i = 0; i < 4; i++) {
                float4 v = src[i];
                tmp[i*4+0] = f2bf(v.x); tmp[i*4+1] = f2bf(v.y);
                tmp[i*4+2] = f2bf(v.z); tmp[i*4+3] = f2bf(v.w);
            }
            *(uint4*)&As[sr][sh]     = *(const uint4*)&tmp[0];
            *(uint4*)&As[sr][sh + 8] = *(const uint4*)&tmp[8];
        } else {
            const unsigned short* A = (const unsigned short*)Ap;
            const uint4* src = (const uint4*)(A + (size_t)(tm * BM + sr) * K + k0 + sh);
            *(uint4*)&As[sr][sh]     = src[0];
            *(uint4*)&As[sr][sh + 8] = src[1];
        }
        {
            const float4* src = (const float4*)(Bw + (size_t)(tn * BN + sr) * K + k0 + sh);
            unsigned short tmp[16];
            #pragma unroll
            for (int i = 0; i < 4; i++) {
                float4 v = src[i];
                tmp[i*4+0] = f2bf(v.x); tmp[i*4+1] = f2bf(v.y);
                tmp[i*4+2] = f2bf(v.z); tmp[i*4+3] = f2bf(v.w);
            }
            *(uint4*)&Bs[sr][sh]     = *(const uint4*)&tmp[0];
            *(uint4*)&Bs[sr][sh + 8] = *(const uint4*)&tmp[8];
        }
        __syncthreads();

        bf16x8 af[4], bfr[4];
        #pragma unroll
        for (int m = 0; m < 4; m++) af[m]  = *(const bf16x8*)&As[wm + m * 16 + lr][lg * 8];
        #pragma unroll
        for (int n = 0; n < 4; n++) bfr[n] = *(const bf16x8*)&Bs[wn + n * 16 + lr][lg * 8];
        #pragma unroll
        for (int m = 0; m < 4; m++)
            #pragma unroll
            for (int n = 0; n < 4; n++)
                acc[m][n] = mfma16x16x32(af[m], bfr[n], acc[m][n]);
    }

    // Epilogue. C/D layout: col = lane&15, row = 4*(lane>>4) + reg  [measured m89]
    #pragma unroll
    for (int n = 0; n < 4; n++) {
        const int col = tn * BN + wn + n * 16 + lr;
        const float bv = bias[col];
        #pragma unroll
        for (int m = 0; m < 4; m++) {
            const int row0 = tm * BM + wm + m * 16 + lg * 4;
            #pragma unroll
            for (int r = 0; r < 4; r++) {
                const float v = (acc[m][n][r] + bv) * scale;
                const int row = row0 + r;
                if constexpr (MODE == 0) {
                    const int b_ = row >> 11, s = row & (Sc - 1);
                    const int hh = col >> 6, hd = col & 63;
                    ((unsigned short*)Yp)[(((size_t)(b_ * Hc + hh)) * Sc + s) * HDc + hd] = f2bf(v);
                } else {
                    ((float*)Yp)[(size_t)row * N + col] = v;
                }
            }
        }
    }
}

// Flash attention. Q/K/V: bf16 [B,H,S,HD] (Q pre-scaled by SCALE). ctx: bf16 [B,S,D].
// Swapped QK^T (S^T = K*Q^T) so softmax rows are lane-local; online softmax; P
// re-laid-out through wave-private LDS into PV A-fragments.
__global__ __launch_bounds__(256) void attn_fwd(
    const unsigned short* __restrict__ Q, const unsigned short* __restrict__ Kg,
    const unsigned short* __restrict__ Vg, unsigned short* __restrict__ ctx)
{
    __shared__ short Ks[64][72];        // K-tile rows [k][hd]
    __shared__ short Vt[64][72];        // V-tile transposed [hd][k]
    __shared__ short Pl[4][16][72];     // per-wave P [q][k]

    const int tid = threadIdx.x, lane = tid & 63, w = tid >> 6;
    const int lr = lane & 15, lg = lane >> 4;
    const int bh = blockIdx.x >> 5;   // (b*H + h)
    const int qt = blockIdx.x & 31;   // q-tile of 64 rows
    const size_t base = (size_t)bh * Sc * HDc;
    const unsigned short* Qb = Q  + base;
    const unsigned short* Kb = Kg + base;
    const unsigned short* Vb = Vg + base;

    // Q B-fragments, hoisted: B[kd=hd][j=q]: lane holds Q[q0+lr][32*kk + 8*lg + e]
    const int qrow = qt * 64 + w * 16 + lr;
    bf16x8 qf[2];
    qf[0] = *(const bf16x8*)&Qb[(size_t)qrow * HDc + lg * 8];
    qf[1] = *(const bf16x8*)&Qb[(size_t)qrow * HDc + 32 + lg * 8];

    float m_run = -1e30f, l_run = 0.f;
    f32x4 acc[4];   // ctx: row q = 4*lg + r, col hd = h*16 + lr
    #pragma unroll
    for (int h = 0; h < 4; h++) acc[h] = (f32x4){0.f, 0.f, 0.f, 0.f};

    const int srow = tid >> 2, sc16 = (tid & 3) * 16;

    for (int kt = 0; kt < Sc / 64; ++kt) {
        __syncthreads();
        {   // stage K row-major + V transposed
            const uint4* ks = (const uint4*)&Kb[(size_t)(kt * 64 + srow) * HDc + sc16];
            *(uint4*)&Ks[srow][sc16]     = ks[0];
            *(uint4*)&Ks[srow][sc16 + 8] = ks[1];
            const uint4* vs = (const uint4*)&Vb[(size_t)(kt * 64 + srow) * HDc + sc16];
            union { uint4 v; unsigned short u[8]; } v0, v1;
            v0.v = vs[0]; v1.v = vs[1];
            #pragma unroll
            for (int e = 0; e < 8; e++) Vt[sc16 + e][srow]     = (short)v0.u[e];
            #pragma unroll
            for (int e = 0; e < 8; e++) Vt[sc16 + 8 + e][srow] = (short)v1.u[e];
        }
        __syncthreads();

        // S^T[k][q]: C row = k-local = 4*lg + r, col = q = lr (Q pre-scaled)
        f32x4 sf[4];
        #pragma unroll
        for (int kb = 0; kb < 4; kb++) {
            bf16x8 a0 = *(const bf16x8*)&Ks[kb * 16 + lr][lg * 8];
            bf16x8 a1 = *(const bf16x8*)&Ks[kb * 16 + lr][32 + lg * 8];
            f32x4 c = (f32x4){0.f, 0.f, 0.f, 0.f};
            c = mfma16x16x32(a0, qf[0], c);
            c = mfma16x16x32(a1, qf[1], c);
            sf[kb] = c;
        }

        // online softmax for q = lr (16 k-values/lane; reduce across 4 lane-groups)
        float tmax = -1e30f;
        #pragma unroll
        for (int kb = 0; kb < 4; kb++)
            #pragma unroll
            for (int r = 0; r < 4; r++) tmax = fmaxf(tmax, sf[kb][r]);
        tmax = fmaxf(tmax, __shfl_xor(tmax, 16));
        tmax = fmaxf(tmax, __shfl_xor(tmax, 32));
        const float mnew = fmaxf(m_run, tmax);

        float psum = 0.f;
        s16x4 pq[4];
        #pragma unroll
        for (int kb = 0; kb < 4; kb++) {
            #pragma unroll
            for (int r = 0; r < 4; r++) {
                const float pv = __expf(sf[kb][r] - mnew);
                psum += pv;
                pq[kb][r] = (short)f2bf(pv);
            }
        }
        psum += __shfl_xor(psum, 16);
        psum += __shfl_xor(psum, 32);

        const float cf = __expf(m_run - mnew);   // first tile: exp(-huge) = 0
        l_run = l_run * cf + psum;
        m_run = mnew;

        #pragma unroll
        for (int r = 0; r < 4; r++) {            // rescale ctx rows q = 4*lg + r
            const float cfr = __shfl(cf, 4 * lg + r);
            #pragma unroll
            for (int h = 0; h < 4; h++) acc[h][r] *= cfr;
        }

        // P -> wave-private LDS [q][k], then read back as PV A-fragments
        #pragma unroll
        for (int kb = 0; kb < 4; kb++)
            *(s16x4*)&Pl[w][lr][kb * 16 + lg * 4] = pq[kb];

        bf16x8 pa0 = *(const bf16x8*)&Pl[w][lr][lg * 8];
        bf16x8 pa1 = *(const bf16x8*)&Pl[w][lr][32 + lg * 8];

        #pragma unroll
        for (int h = 0; h < 4; h++) {
            bf16x8 b0 = *(const bf16x8*)&Vt[h * 16 + lr][lg * 8];
            bf16x8 b1 = *(const bf16x8*)&Vt[h * 16 + lr][32 + lg * 8];
            acc[h] = mfma16x16x32(pa0, b0, acc[h]);
            acc[h] = mfma16x16x32(pa1, b1, acc[h]);
        }
    }

    const float linv = 1.f / l_run;
    const int b_ = bh >> 4, hh = bh & 15;
    #pragma unroll
    for (int r = 0; r < 4; r++) {
        const float lv = __shfl(linv, 4 * lg + r);
        const int s = qt * 64 + w * 16 + 4 * lg + r;
        const size_t ro = ((size_t)b_ * Sc + s) * Dc + (size_t)hh * HDc;
        #pragma unroll
        for (int h = 0; h < 4; h++)
            ctx[ro + h * 16 + lr] = f2bf(acc[h][r] * lv);
    }
}

extern "C" void kernel_launch(void* const* d_in, const int* in_sizes, int n_in,
                              void* d_out, int out_size, void* d_ws, size_t ws_size,
                              hipStream_t stream)
{
    const float* query = (const float*)d_in[0];
    const float* key   = (const float*)d_in[1];
    const float* value = (const float*)d_in[2];
    const float* Wq = (const float*)d_in[3];
    const float* bq = (const float*)d_in[4];
    const float* Wk = (const float*)d_in[5];
    const float* bk = (const float*)d_in[6];
    const float* Wv = (const float*)d_in[7];
    const float* bv = (const float*)d_in[8];
    const float* Wo = (const float*)d_in[9];
    const float* bo = (const float*)d_in[10];

    const size_t HE = (size_t)Bc * Hc * Sc * HDc;  // 4M elems
    unsigned short* Qh  = (unsigned short*)d_ws;
    unsigned short* Kh  = Qh + HE;
    unsigned short* Vh  = Kh + HE;
    unsigned short* cx  = Vh + HE;

    dim3 blk(256);
    gemm_bt<false, 0><<<256, blk, 0, stream>>>(query, Wq, bq, Qh, SCALEc);
    gemm_bt<false, 0><<<256, blk, 0, stream>>>(key,   Wk, bk, Kh, 1.0f);
    gemm_bt<false, 0><<<256, blk, 0, stream>>>(value, Wv, bv, Vh, 1.0f);
    attn_fwd<<<Bc * Hc * (Sc / 64), blk, 0, stream>>>(Qh, Kh, Vh, cx);
    gemm_bt<true, 1><<<256, blk, 0, stream>>>(cx, Wo, bo, d_out, 1.0f);
}

// Round 2
// 183.905 us; speedup vs baseline: 1.4556x; 1.4556x over previous
//
#include <hip/hip_runtime.h>
#include <hip/hip_bf16.h>

#define DEVFN __device__ __forceinline__

typedef __attribute__((ext_vector_type(8))) short bf16x8;   // 8 bf16 = 4 VGPR
typedef __attribute__((ext_vector_type(4))) short s16x4;
typedef __attribute__((ext_vector_type(4))) float f32x4;

constexpr int Bc = 2, Sc = 2048, Dc = 1024, Hc = 16, HDc = 64;
constexpr float SCALEc = 0.125f;  // HD^-0.5

DEVFN unsigned short f2bf(float f) {  // RNE fp32 -> bf16
    union { float f; unsigned int u; } x; x.f = f;
    return (unsigned short)((x.u + 0x7fffu + ((x.u >> 16) & 1u)) >> 16);
}

DEVFN f32x4 mfma16(bf16x8 a, bf16x8 b, f32x4 c) {
    return __builtin_amdgcn_mfma_f32_16x16x32_bf16(a, b, c, 0, 0, 0);
}

DEVFN void gload16(const void* g, void* l) {  // async global->LDS, 16B/lane, lds dest = base + lane*16
    __builtin_amdgcn_global_load_lds((const __attribute__((address_space(1))) void*)g,
                                     (__attribute__((address_space(3))) void*)l, 16, 0, 0);
}

// ---- weights fp32 -> bf16 (4 x 1M elems, 8 elems/thread) ----
__global__ __launch_bounds__(256) void wcvt(
    const float* __restrict__ s0, const float* __restrict__ s1,
    const float* __restrict__ s2, const float* __restrict__ s3,
    unsigned short* __restrict__ d0, unsigned short* __restrict__ d1,
    unsigned short* __restrict__ d2, unsigned short* __restrict__ d3)
{
    const int t = blockIdx.x * 256 + threadIdx.x;      // 131072 threads per tensor
    const int which = t >> 17;
    const int off = (t & 131071) * 8;
    const float* s = which == 0 ? s0 : which == 1 ? s1 : which == 2 ? s2 : s3;
    unsigned short* d = which == 0 ? d0 : which == 1 ? d1 : which == 2 ? d2 : d3;
    float4 v0 = *(const float4*)(s + off);
    float4 v1 = *(const float4*)(s + off + 4);
    unsigned short t8[8] = {f2bf(v0.x), f2bf(v0.y), f2bf(v0.z), f2bf(v0.w),
                            f2bf(v1.x), f2bf(v1.y), f2bf(v1.z), f2bf(v1.w)};
    *(uint4*)(d + off) = *(const uint4*)t8;
}

// ---- fused QKV projection: 3 GEMMs [4096x1024]·W^T, g = blockIdx>>8 selects tensor.
// A fp32 (reg-staged + cvt), B bf16 via global_load_lds. LDS [128][32] bf16 linear with
// 16B-slot swizzle: slot' = slot ^ ((row>>1)&3)  (64B rows -> 16 consecutive rows spread
// over all 8 positions per 128B bank period; residual 2-way is free per m136).
// g<2: out bf16 [B,H,S,HD] (*scale for Q). g==2: out bf16 transposed [B,H,HD,S] (packed 8B).
__global__ __launch_bounds__(256) void qkv_gemm(
    const float* __restrict__ Aq, const float* __restrict__ Ak, const float* __restrict__ Av,
    const unsigned short* __restrict__ Wqb, const unsigned short* __restrict__ Wkb,
    const unsigned short* __restrict__ Wvb,
    const float* __restrict__ bqp, const float* __restrict__ bkp, const float* __restrict__ bvp,
    unsigned short* __restrict__ Qo, unsigned short* __restrict__ Ko, unsigned short* __restrict__ Vto)
{
    __shared__ short As[128 * 32];
    __shared__ short Bs[128 * 32];

    const int g = blockIdx.x >> 8;
    const float* A = g == 0 ? Aq : g == 1 ? Ak : Av;
    const unsigned short* Bw = g == 0 ? Wqb : g == 1 ? Wkb : Wvb;
    const float* bias = g == 0 ? bqp : g == 1 ? bkp : bvp;
    const float scale = g == 0 ? SCALEc : 1.0f;

    const int tid = threadIdx.x, lane = tid & 63, w = tid >> 6;
    const int lr = lane & 15, lg = lane >> 4;
    const int bid = blockIdx.x & 255;
    const int tm = bid & 31, tn = bid >> 5;
    const int wm = (w >> 1) * 64, wn = (w & 1) * 64;

    // A staging: row ar (2 threads/row), 16 floats = logical slots {abf, abf+1}
    const int ar = tid >> 1, abf = (tid & 1) * 2;
    const float* Aptr = A + (size_t)(tm * 128 + ar) * 1024 + abf * 8;
    const int fa = (ar >> 1) & 3;
    short* AW0 = &As[ar * 32 + ((abf)     ^ fa) * 8];
    short* AW1 = &As[ar * 32 + ((abf + 1) ^ fa) * 8];

    // B staging: wave w owns chunks {2w, 2w+1}; chunk c: lane -> row c*16+(l>>2), slotp l&3
    const int bc0 = 2 * w, bc1 = 2 * w + 1;
    const int br0 = bc0 * 16 + (lane >> 2), br1 = bc1 * 16 + (lane >> 2);
    const unsigned short* Bp0 = Bw + (size_t)(tn * 128 + br0) * 1024 + ((lane & 3) ^ ((br0 >> 1) & 3)) * 8;
    const unsigned short* Bp1 = Bw + (size_t)(tn * 128 + br1) * 1024 + ((lane & 3) ^ ((br1 >> 1) & 3)) * 8;
    short* BL0 = &Bs[bc0 * 512];
    short* BL1 = &Bs[bc1 * 512];

    f32x4 acc[4][4] = {};
    const int fread = (lr >> 1) & 3;

    for (int k0 = 0; k0 < 1024; k0 += 32) {
        float4 a0 = *(const float4*)(Aptr + 0);
        float4 a1 = *(const float4*)(Aptr + 4);
        float4 a2 = *(const float4*)(Aptr + 8);
        float4 a3 = *(const float4*)(Aptr + 12);
        Aptr += 32;
        __syncthreads();                       // prior frag reads done
        gload16(Bp0 + k0, BL0);
        gload16(Bp1 + k0, BL1);
        unsigned short t8[16] = {
            f2bf(a0.x), f2bf(a0.y), f2bf(a0.z), f2bf(a0.w),
            f2bf(a1.x), f2bf(a1.y), f2bf(a1.z), f2bf(a1.w),
            f2bf(a2.x), f2bf(a2.y), f2bf(a2.z), f2bf(a2.w),
            f2bf(a3.x), f2bf(a3.y), f2bf(a3.z), f2bf(a3.w)};
        *(uint4*)AW0 = *(const uint4*)&t8[0];
        *(uint4*)AW1 = *(const uint4*)&t8[8];
        __syncthreads();                       // drains vmcnt (gload) + lgkm (ds_write)

        bf16x8 af[4], bfv[4];
        #pragma unroll
        for (int m = 0; m < 4; m++) {
            const int row = wm + m * 16 + lr;
            af[m] = *(const bf16x8*)&As[row * 32 + (lg ^ fread) * 8];
        }
        #pragma unroll
        for (int n = 0; n < 4; n++) {
            const int row = wn + n * 16 + lr;
            bfv[n] = *(const bf16x8*)&Bs[row * 32 + (lg ^ fread) * 8];
        }
        #pragma unroll
        for (int m = 0; m < 4; m++)
            #pragma unroll
            for (int n = 0; n < 4; n++)
                acc[m][n] = mfma16(af[m], bfv[n], acc[m][n]);
    }

    // C/D layout: col = lr, row = 4*lg + r [m89]
    if (g < 2) {
        unsigned short* Y = g == 0 ? Qo : Ko;
        #pragma unroll
        for (int n = 0; n < 4; n++) {
            const int col = tn * 128 + wn + n * 16 + lr;
            const float bv = bias[col];
            const int hh = col >> 6, hd = col & 63;
            #pragma unroll
            for (int m = 0; m < 4; m++) {
                const int row0 = tm * 128 + wm + m * 16 + lg * 4;
                const int b_ = row0 >> 11, sQ = row0 & 2047;
                #pragma unroll
                for (int r = 0; r < 4; r++) {
                    const float v = (acc[m][n][r] + bv) * scale;
                    Y[(((size_t)(b_ * Hc + hh)) * Sc + (sQ + r)) * HDc + hd] = f2bf(v);
                }
            }
        }
    } else {  // V transposed: [B,H,HD,S]; 4 consecutive s -> one 8B store
        #pragma unroll
        for (int n = 0; n < 4; n++) {
            const int col = tn * 128 + wn + n * 16 + lr;
            const float bv = bias[col];
            const int hh = col >> 6, hd = col & 63;
            #pragma unroll
            for (int m = 0; m < 4; m++) {
                const int row0 = tm * 128 + wm + m * 16 + lg * 4;
                const int b_ = row0 >> 11, sQ = row0 & 2047;
                unsigned long long pk = 0;
                #pragma unroll
                for (int r = 0; r < 4; r++)
                    pk |= (unsigned long long)f2bf(acc[m][n][r] + bv) << (16 * r);
                *(unsigned long long*)&Vto[(((size_t)(b_ * Hc + hh)) * HDc + hd) * Sc + sQ] = pk;
            }
        }
    }
}

// ---- output projection: A bf16 (ctx), B bf16 (Wo), fp32 out + bias. Full gload_lds. ----
__global__ __launch_bounds__(256) void out_gemm(
    const unsigned short* __restrict__ Ab, const unsigned short* __restrict__ Bw,
    const float* __restrict__ bias, float* __restrict__ Y)
{
    __shared__ short As[128 * 32];
    __shared__ short Bs[128 * 32];
    const int tid = threadIdx.x, lane = tid & 63, w = tid >> 6;
    const int lr = lane & 15, lg = lane >> 4;
    const int tm = blockIdx.x & 31, tn = blockIdx.x >> 5;
    const int wm = (w >> 1) * 64, wn = (w & 1) * 64;

    const int c0 = 2 * w, c1 = 2 * w + 1;
    const int r0 = c0 * 16 + (lane >> 2), r1 = c1 * 16 + (lane >> 2);
    const int sl0 = ((lane & 3) ^ ((r0 >> 1) & 3)) * 8, sl1 = ((lane & 3) ^ ((r1 >> 1) & 3)) * 8;
    const unsigned short* Ap0 = Ab + (size_t)(tm * 128 + r0) * 1024 + sl0;
    const unsigned short* Ap1 = Ab + (size_t)(tm * 128 + r1) * 1024 + sl1;
    const unsigned short* Bp0 = Bw + (size_t)(tn * 128 + r0) * 1024 + sl0;
    const unsigned short* Bp1 = Bw + (size_t)(tn * 128 + r1) * 1024 + sl1;
    short* AL0 = &As[c0 * 512]; short* AL1 = &As[c1 * 512];
    short* BL0 = &Bs[c0 * 512]; short* BL1 = &Bs[c1 * 512];

    f32x4 acc[4][4] = {};
    const int fread = (lr >> 1) & 3;

    for (int k0 = 0; k0 < 1024; k0 += 32) {
        __syncthreads();
        gload16(Ap0 + k0, AL0);
        gload16(Ap1 + k0, AL1);
        gload16(Bp0 + k0, BL0);
        gload16(Bp1 + k0, BL1);
        __syncthreads();

        bf16x8 af[4], bfv[4];
        #pragma unroll
        for (int m = 0; m < 4; m++) {
            const int row = wm + m * 16 + lr;
            af[m] = *(const bf16x8*)&As[row * 32 + (lg ^ fread) * 8];
        }
        #pragma unroll
        for (int n = 0; n < 4; n++) {
            const int row = wn + n * 16 + lr;
            bfv[n] = *(const bf16x8*)&Bs[row * 32 + (lg ^ fread) * 8];
        }
        #pragma unroll
        for (int m = 0; m < 4; m++)
            #pragma unroll
            for (int n = 0; n < 4; n++)
                acc[m][n] = mfma16(af[m], bfv[n], acc[m][n]);
    }

    #pragma unroll
    for (int n = 0; n < 4; n++) {
        const int col = tn * 128 + wn + n * 16 + lr;
        const float bv = bias[col];
        #pragma unroll
        for (int m = 0; m < 4; m++) {
            const int row0 = tm * 128 + wm + m * 16 + lg * 4;
            #pragma unroll
            for (int r = 0; r < 4; r++)
                Y[(size_t)(row0 + r) * 1024 + col] = acc[m][n][r] + bv;
        }
    }
}

// ---- flash attention. Q,K: bf16 [B,H,S,HD] (Q pre-scaled); V: bf16 [B,H,HD,S] (pre-transposed).
__global__ __launch_bounds__(256) void attn_fwd(
    const unsigned short* __restrict__ Q, const unsigned short* __restrict__ Kg,
    const unsigned short* __restrict__ Vtg, unsigned short* __restrict__ ctx)
{
    __shared__ short Ks[64][72];   // K-tile [k][hd]
    __shared__ short Vs[64][72];   // V^T-tile [hd][k]
    __shared__ short Pl[4][16][72];

    const int tid = threadIdx.x, lane = tid & 63, w = tid >> 6;
    const int lr = lane & 15, lg = lane >> 4;
    const int bh = blockIdx.x >> 5;
    const int qt = blockIdx.x & 31;
    const unsigned short* Qb = Q   + (size_t)bh * Sc * HDc;
    const unsigned short* Kb = Kg  + (size_t)bh * Sc * HDc;
    const unsigned short* Vb = Vtg + (size_t)bh * HDc * Sc;  // [64][2048]

    const int qrow = qt * 64 + w * 16 + lr;
    bf16x8 qf[2];
    qf[0] = *(const bf16x8*)&Qb[(size_t)qrow * HDc + lg * 8];
    qf[1] = *(const bf16x8*)&Qb[(size_t)qrow * HDc + 32 + lg * 8];

    float m_run = -1e30f, l_run = 0.f;
    f32x4 acc[4];
    #pragma unroll
    for (int h = 0; h < 4; h++) acc[h] = (f32x4){0.f, 0.f, 0.f, 0.f};

    const int srow = tid >> 2, sc16 = (tid & 3) * 16;

    for (int kt = 0; kt < Sc / 64; ++kt) {
        __syncthreads();
        {   // both tiles staged with vectorized conflict-light writes
            const uint4* ks = (const uint4*)&Kb[(size_t)(kt * 64 + srow) * HDc + sc16];
            *(uint4*)&Ks[srow][sc16]     = ks[0];
            *(uint4*)&Ks[srow][sc16 + 8] = ks[1];
            const uint4* vs = (const uint4*)&Vb[(size_t)srow * Sc + kt * 64 + sc16];
            *(uint4*)&Vs[srow][sc16]     = vs[0];
            *(uint4*)&Vs[srow][sc16 + 8] = vs[1];
        }
        __syncthreads();

        // S^T = K·Q^T: C row = k-local = 4*lg+r, col = q = lr
        f32x4 sf[4];
        #pragma unroll
        for (int kb = 0; kb < 4; kb++) {
            bf16x8 a0 = *(const bf16x8*)&Ks[kb * 16 + lr][lg * 8];
            bf16x8 a1 = *(const bf16x8*)&Ks[kb * 16 + lr][32 + lg * 8];
            f32x4 c = (f32x4){0.f, 0.f, 0.f, 0.f};
            c = mfma16(a0, qf[0], c);
            c = mfma16(a1, qf[1], c);
            sf[kb] = c;
        }

        float tmax = -1e30f;
        #pragma unroll
        for (int kb = 0; kb < 4; kb++)
            #pragma unroll
            for (int r = 0; r < 4; r++) tmax = fmaxf(tmax, sf[kb][r]);
        tmax = fmaxf(tmax, __shfl_xor(tmax, 16));
        tmax = fmaxf(tmax, __shfl_xor(tmax, 32));
        const float mnew = fmaxf(m_run, tmax);

        float psum = 0.f;
        s16x4 pq[4];
        #pragma unroll
        for (int kb = 0; kb < 4; kb++) {
            #pragma unroll
            for (int r = 0; r < 4; r++) {
                const float pv = __expf(sf[kb][r] - mnew);
                psum += pv;
                pq[kb][r] = (short)f2bf(pv);
            }
        }
        psum += __shfl_xor(psum, 16);
        psum += __shfl_xor(psum, 32);

        const float cf = __expf(m_run - mnew);
        l_run = l_run * cf + psum;
        m_run = mnew;

        #pragma unroll
        for (int r = 0; r < 4; r++) {
            const float cfr = __shfl(cf, 4 * lg + r);
            #pragma unroll
            for (int h = 0; h < 4; h++) acc[h][r] *= cfr;
        }

        #pragma unroll
        for (int kb = 0; kb < 4; kb++)
            *(s16x4*)&Pl[w][lr][kb * 16 + lg * 4] = pq[kb];

        bf16x8 pa0 = *(const bf16x8*)&Pl[w][lr][lg * 8];
        bf16x8 pa1 = *(const bf16x8*)&Pl[w][lr][32 + lg * 8];

        #pragma unroll
        for (int h = 0; h < 4; h++) {
            bf16x8 b0 = *(const bf16x8*)&Vs[h * 16 + lr][lg * 8];
            bf16x8 b1 = *(const bf16x8*)&Vs[h * 16 + lr][32 + lg * 8];
            acc[h] = mfma16(pa0, b0, acc[h]);
            acc[h] = mfma16(pa1, b1, acc[h]);
        }
    }

    const float linv = 1.f / l_run;
    const int b_ = bh >> 4, hh = bh & 15;
    #pragma unroll
    for (int r = 0; r < 4; r++) {
        const float lv = __shfl(linv, 4 * lg + r);
        const int s = qt * 64 + w * 16 + 4 * lg + r;
        const size_t ro = ((size_t)b_ * Sc + s) * Dc + (size_t)hh * HDc;
        #pragma unroll
        for (int h = 0; h < 4; h++)
            ctx[ro + h * 16 + lr] = f2bf(acc[h][r] * lv);
    }
}

extern "C" void kernel_launch(void* const* d_in, const int* in_sizes, int n_in,
                              void* d_out, int out_size, void* d_ws, size_t ws_size,
                              hipStream_t stream)
{
    const float* query = (const float*)d_in[0];
    const float* key   = (const float*)d_in[1];
    const float* value = (const float*)d_in[2];
    const float* Wq = (const float*)d_in[3];
    const float* bq = (const float*)d_in[4];
    const float* Wk = (const float*)d_in[5];
    const float* bk = (const float*)d_in[6];
    const float* Wv = (const float*)d_in[7];
    const float* bv = (const float*)d_in[8];
    const float* Wo = (const float*)d_in[9];
    const float* bo = (const float*)d_in[10];

    unsigned short* wqb = (unsigned short*)d_ws;     // 4 x 1M bf16 weights
    unsigned short* wkb = wqb + 1048576;
    unsigned short* wvb = wkb + 1048576;
    unsigned short* wob = wvb + 1048576;
    unsigned short* Qh  = wob + 1048576;             // 4M each
    unsigned short* Kh  = Qh + 4194304;
    unsigned short* Vth = Kh + 4194304;
    unsigned short* cx  = Vth + 4194304;             // total 40 MB

    wcvt<<<2048, 256, 0, stream>>>(Wq, Wk, Wv, Wo, wqb, wkb, wvb, wob);
    qkv_gemm<<<768, 256, 0, stream>>>(query, key, value, wqb, wkb, wvb,
                                      bq, bk, bv, Qh, Kh, Vth);
    attn_fwd<<<Bc * Hc * (Sc / 64), 256, 0, stream>>>(Qh, Kh, Vth, cx);
    out_gemm<<<256, 256, 0, stream>>>(cx, wob, bo, (float*)d_out);
}

// Round 3
// 165.175 us; speedup vs baseline: 1.6206x; 1.1134x over previous
//
#include <hip/hip_runtime.h>
#include <hip/hip_bf16.h>

#define DEVFN __device__ __forceinline__

typedef __attribute__((ext_vector_type(8))) short bf16x8;   // 8 bf16 = 4 VGPR
typedef __attribute__((ext_vector_type(4))) short s16x4;
typedef __attribute__((ext_vector_type(4))) float f32x4;

constexpr int Bc = 2, Sc = 2048, Dc = 1024, Hc = 16, HDc = 64;
constexpr float SCALEc = 0.125f;  // HD^-0.5

DEVFN unsigned short f2bf(float f) {  // RNE fp32 -> bf16
    union { float f; unsigned int u; } x; x.f = f;
    return (unsigned short)((x.u + 0x7fffu + ((x.u >> 16) & 1u)) >> 16);
}

DEVFN f32x4 mfma16(bf16x8 a, bf16x8 b, f32x4 c) {
    return __builtin_amdgcn_mfma_f32_16x16x32_bf16(a, b, c, 0, 0, 0);
}

DEVFN void gload16(const void* g, void* l) {  // async global->LDS, 16B/lane, dest = base + lane*16
    __builtin_amdgcn_global_load_lds((const __attribute__((address_space(1))) void*)g,
                                     (__attribute__((address_space(3))) void*)l, 16, 0, 0);
}

// ---- one streaming pass: fp32 -> bf16 for q,k,v (4M elems each) + Wq,Wk,Wv,Wo (1M each) ----
__global__ __launch_bounds__(256) void cvt_all(
    const float* __restrict__ q, const float* __restrict__ k, const float* __restrict__ v,
    const float* __restrict__ wq, const float* __restrict__ wk,
    const float* __restrict__ wv, const float* __restrict__ wo,
    unsigned short* __restrict__ qb, unsigned short* __restrict__ kb, unsigned short* __restrict__ vb,
    unsigned short* __restrict__ wqb, unsigned short* __restrict__ wkb,
    unsigned short* __restrict__ wvb, unsigned short* __restrict__ wob)
{
    const unsigned t = blockIdx.x * 256 + threadIdx.x;  // 2M threads, 8 elems each
    const float* s; unsigned short* d; unsigned local;
    if (t < (3u << 19)) {                     // activations: 3 x 524288 threads
        const unsigned which = t >> 19; local = t & ((1u << 19) - 1);
        s = which == 0 ? q : which == 1 ? k : v;
        d = which == 0 ? qb : which == 1 ? kb : vb;
    } else {                                  // weights: 4 x 131072 threads
        const unsigned t2 = t - (3u << 19);
        const unsigned which = t2 >> 17; local = t2 & ((1u << 17) - 1);
        s = which == 0 ? wq : which == 1 ? wk : which == 2 ? wv : wo;
        d = which == 0 ? wqb : which == 1 ? wkb : which == 2 ? wvb : wob;
    }
    const size_t off = (size_t)local * 8;
    float4 v0 = *(const float4*)(s + off);
    float4 v1 = *(const float4*)(s + off + 4);
    unsigned short t8[8] = {f2bf(v0.x), f2bf(v0.y), f2bf(v0.z), f2bf(v0.w),
                            f2bf(v1.x), f2bf(v1.y), f2bf(v1.z), f2bf(v1.w)};
    *(uint4*)(d + off) = *(const uint4*)t8;
}

// ---- fused QKV projection, pure bf16, m97 structure (global_load_lds both operands).
// LDS [128][32] bf16 with 16B-slot swizzle slot' = slot ^ ((row>>1)&3) applied to the
// pre-swizzled GLOBAL source (gload_lds dest must stay linear) and to the ds_read addr.
// g<2: out bf16 head-permuted [B,H,S,HD] (*SCALE for Q). g==2: out bf16 [B,H,HD,S].
__global__ __launch_bounds__(256) void qkv_gemm(
    const unsigned short* __restrict__ Aq, const unsigned short* __restrict__ Ak,
    const unsigned short* __restrict__ Av,
    const unsigned short* __restrict__ Wqb, const unsigned short* __restrict__ Wkb,
    const unsigned short* __restrict__ Wvb,
    const float* __restrict__ bqp, const float* __restrict__ bkp, const float* __restrict__ bvp,
    unsigned short* __restrict__ Qo, unsigned short* __restrict__ Ko, unsigned short* __restrict__ Vto)
{
    __shared__ short As[128 * 32];
    __shared__ short Bs[128 * 32];

    const int g = blockIdx.x >> 8;
    const unsigned short* A  = g == 0 ? Aq  : g == 1 ? Ak  : Av;
    const unsigned short* Bw = g == 0 ? Wqb : g == 1 ? Wkb : Wvb;
    const float* bias = g == 0 ? bqp : g == 1 ? bkp : bvp;
    const float scale = g == 0 ? SCALEc : 1.0f;

    const int tid = threadIdx.x, lane = tid & 63, w = tid >> 6;
    const int lr = lane & 15, lg = lane >> 4;
    const int bid = blockIdx.x & 255;
    const int tm = bid & 31, tn = bid >> 5;
    const int wm = (w >> 1) * 64, wn = (w & 1) * 64;

    // staging: wave w owns 16-row chunks {2w, 2w+1}; chunk c: lane -> row c*16+(l>>2), slot l&3
    const int c0 = 2 * w, c1 = 2 * w + 1;
    const int r0 = c0 * 16 + (lane >> 2), r1 = c1 * 16 + (lane >> 2);
    const int sl0 = ((lane & 3) ^ ((r0 >> 1) & 3)) * 8, sl1 = ((lane & 3) ^ ((r1 >> 1) & 3)) * 8;
    const unsigned short* Ap0 = A  + (size_t)(tm * 128 + r0) * 1024 + sl0;
    const unsigned short* Ap1 = A  + (size_t)(tm * 128 + r1) * 1024 + sl1;
    const unsigned short* Bp0 = Bw + (size_t)(tn * 128 + r0) * 1024 + sl0;
    const unsigned short* Bp1 = Bw + (size_t)(tn * 128 + r1) * 1024 + sl1;
    short* AL0 = &As[c0 * 512]; short* AL1 = &As[c1 * 512];
    short* BL0 = &Bs[c0 * 512]; short* BL1 = &Bs[c1 * 512];

    f32x4 acc[4][4] = {};
    const int fread = (lr >> 1) & 3;

    for (int k0 = 0; k0 < 1024; k0 += 32) {
        __syncthreads();
        gload16(Ap0 + k0, AL0);
        gload16(Ap1 + k0, AL1);
        gload16(Bp0 + k0, BL0);
        gload16(Bp1 + k0, BL1);
        __syncthreads();

        bf16x8 af[4], bfv[4];
        #pragma unroll
        for (int m = 0; m < 4; m++) {
            const int row = wm + m * 16 + lr;
            af[m] = *(const bf16x8*)&As[row * 32 + (lg ^ fread) * 8];
        }
        #pragma unroll
        for (int n = 0; n < 4; n++) {
            const int row = wn + n * 16 + lr;
            bfv[n] = *(const bf16x8*)&Bs[row * 32 + (lg ^ fread) * 8];
        }
        #pragma unroll
        for (int m = 0; m < 4; m++)
            #pragma unroll
            for (int n = 0; n < 4; n++)
                acc[m][n] = mfma16(af[m], bfv[n], acc[m][n]);
    }

    // C/D layout: col = lr, row = 4*lg + r [m89]
    if (g < 2) {
        unsigned short* Y = g == 0 ? Qo : Ko;
        #pragma unroll
        for (int n = 0; n < 4; n++) {
            const int col = tn * 128 + wn + n * 16 + lr;
            const float bv = bias[col];
            const int hh = col >> 6, hd = col & 63;
            #pragma unroll
            for (int m = 0; m < 4; m++) {
                const int row0 = tm * 128 + wm + m * 16 + lg * 4;
                const int b_ = row0 >> 11, sQ = row0 & 2047;
                #pragma unroll
                for (int r = 0; r < 4; r++) {
                    const float val = (acc[m][n][r] + bv) * scale;
                    Y[(((size_t)(b_ * Hc + hh)) * Sc + (sQ + r)) * HDc + hd] = f2bf(val);
                }
            }
        }
    } else {  // V transposed [B,H,HD,S]; 4 consecutive s -> one 8B store
        #pragma unroll
        for (int n = 0; n < 4; n++) {
            const int col = tn * 128 + wn + n * 16 + lr;
            const float bv = bias[col];
            const int hh = col >> 6, hd = col & 63;
            #pragma unroll
            for (int m = 0; m < 4; m++) {
                const int row0 = tm * 128 + wm + m * 16 + lg * 4;
                const int b_ = row0 >> 11, sQ = row0 & 2047;
                unsigned long long pk = 0;
                #pragma unroll
                for (int r = 0; r < 4; r++)
                    pk |= (unsigned long long)f2bf(acc[m][n][r] + bv) << (16 * r);
                *(unsigned long long*)&Vto[(((size_t)(b_ * Hc + hh)) * HDc + hd) * Sc + sQ] = pk;
            }
        }
    }
}

// ---- output projection: A bf16 (ctx), B bf16 (Wo), fp32 out + bias ----
__global__ __launch_bounds__(256) void out_gemm(
    const unsigned short* __restrict__ Ab, const unsigned short* __restrict__ Bw,
    const float* __restrict__ bias, float* __restrict__ Y)
{
    __shared__ short As[128 * 32];
    __shared__ short Bs[128 * 32];
    const int tid = threadIdx.x, lane = tid & 63, w = tid >> 6;
    const int lr = lane & 15, lg = lane >> 4;
    const int tm = blockIdx.x & 31, tn = blockIdx.x >> 5;
    const int wm = (w >> 1) * 64, wn = (w & 1) * 64;

    const int c0 = 2 * w, c1 = 2 * w + 1;
    const int r0 = c0 * 16 + (lane >> 2), r1 = c1 * 16 + (lane >> 2);
    const int sl0 = ((lane & 3) ^ ((r0 >> 1) & 3)) * 8, sl1 = ((lane & 3) ^ ((r1 >> 1) & 3)) * 8;
    const unsigned short* Ap0 = Ab + (size_t)(tm * 128 + r0) * 1024 + sl0;
    const unsigned short* Ap1 = Ab + (size_t)(tm * 128 + r1) * 1024 + sl1;
    const unsigned short* Bp0 = Bw + (size_t)(tn * 128 + r0) * 1024 + sl0;
    const unsigned short* Bp1 = Bw + (size_t)(tn * 128 + r1) * 1024 + sl1;
    short* AL0 = &As[c0 * 512]; short* AL1 = &As[c1 * 512];
    short* BL0 = &Bs[c0 * 512]; short* BL1 = &Bs[c1 * 512];

    f32x4 acc[4][4] = {};
    const int fread = (lr >> 1) & 3;

    for (int k0 = 0; k0 < 1024; k0 += 32) {
        __syncthreads();
        gload16(Ap0 + k0, AL0);
        gload16(Ap1 + k0, AL1);
        gload16(Bp0 + k0, BL0);
        gload16(Bp1 + k0, BL1);
        __syncthreads();

        bf16x8 af[4], bfv[4];
        #pragma unroll
        for (int m = 0; m < 4; m++) {
            const int row = wm + m * 16 + lr;
            af[m] = *(const bf16x8*)&As[row * 32 + (lg ^ fread) * 8];
        }
        #pragma unroll
        for (int n = 0; n < 4; n++) {
            const int row = wn + n * 16 + lr;
            bfv[n] = *(const bf16x8*)&Bs[row * 32 + (lg ^ fread) * 8];
        }
        #pragma unroll
        for (int m = 0; m < 4; m++)
            #pragma unroll
            for (int n = 0; n < 4; n++)
                acc[m][n] = mfma16(af[m], bfv[n], acc[m][n]);
    }

    #pragma unroll
    for (int n = 0; n < 4; n++) {
        const int col = tn * 128 + wn + n * 16 + lr;
        const float bv = bias[col];
        #pragma unroll
        for (int m = 0; m < 4; m++) {
            const int row0 = tm * 128 + wm + m * 16 + lg * 4;
            #pragma unroll
            for (int r = 0; r < 4; r++)
                Y[(size_t)(row0 + r) * 1024 + col] = acc[m][n][r] + bv;
        }
    }
}

// ---- flash attention. Q,K: bf16 [B,H,S,HD] (Q pre-scaled); V: bf16 [B,H,HD,S]. ----
__global__ __launch_bounds__(256) void attn_fwd(
    const unsigned short* __restrict__ Q, const unsigned short* __restrict__ Kg,
    const unsigned short* __restrict__ Vtg, unsigned short* __restrict__ ctx)
{
    __shared__ short Ks[64][72];   // K-tile [k][hd]
    __shared__ short Vs[64][72];   // V^T-tile [hd][k]
    __shared__ short Pl[4][16][72];

    const int tid = threadIdx.x, lane = tid & 63, w = tid >> 6;
    const int lr = lane & 15, lg = lane >> 4;
    const int bh = blockIdx.x >> 5;
    const int qt = blockIdx.x & 31;
    const unsigned short* Qb = Q   + (size_t)bh * Sc * HDc;
    const unsigned short* Kb = Kg  + (size_t)bh * Sc * HDc;
    const unsigned short* Vb = Vtg + (size_t)bh * HDc * Sc;  // [64][2048]

    const int qrow = qt * 64 + w * 16 + lr;
    bf16x8 qf[2];
    qf[0] = *(const bf16x8*)&Qb[(size_t)qrow * HDc + lg * 8];
    qf[1] = *(const bf16x8*)&Qb[(size_t)qrow * HDc + 32 + lg * 8];

    float m_run = -1e30f, l_run = 0.f;
    f32x4 acc[4];
    #pragma unroll
    for (int h = 0; h < 4; h++) acc[h] = (f32x4){0.f, 0.f, 0.f, 0.f};

    const int srow = tid >> 2, sc16 = (tid & 3) * 16;

    for (int kt = 0; kt < Sc / 64; ++kt) {
        __syncthreads();
        {
            const uint4* ks = (const uint4*)&Kb[(size_t)(kt * 64 + srow) * HDc + sc16];
            *(uint4*)&Ks[srow][sc16]     = ks[0];
            *(uint4*)&Ks[srow][sc16 + 8] = ks[1];
            const uint4* vs = (const uint4*)&Vb[(size_t)srow * Sc + kt * 64 + sc16];
            *(uint4*)&Vs[srow][sc16]     = vs[0];
            *(uint4*)&Vs[srow][sc16 + 8] = vs[1];
        }
        __syncthreads();

        // S^T = K·Q^T: C row = k-local = 4*lg+r, col = q = lr
        f32x4 sf[4];
        #pragma unroll
        for (int kb = 0; kb < 4; kb++) {
            bf16x8 a0 = *(const bf16x8*)&Ks[kb * 16 + lr][lg * 8];
            bf16x8 a1 = *(const bf16x8*)&Ks[kb * 16 + lr][32 + lg * 8];
            f32x4 c = (f32x4){0.f, 0.f, 0.f, 0.f};
            c = mfma16(a0, qf[0], c);
            c = mfma16(a1, qf[1], c);
            sf[kb] = c;
        }

        float tmax = -1e30f;
        #pragma unroll
        for (int kb = 0; kb < 4; kb++)
            #pragma unroll
            for (int r = 0; r < 4; r++) tmax = fmaxf(tmax, sf[kb][r]);
        tmax = fmaxf(tmax, __shfl_xor(tmax, 16));
        tmax = fmaxf(tmax, __shfl_xor(tmax, 32));
        const float mnew = fmaxf(m_run, tmax);

        float psum = 0.f;
        s16x4 pq[4];
        #pragma unroll
        for (int kb = 0; kb < 4; kb++) {
            #pragma unroll
            for (int r = 0; r < 4; r++) {
                const float pv = __expf(sf[kb][r] - mnew);
                psum += pv;
                pq[kb][r] = (short)f2bf(pv);
            }
        }
        psum += __shfl_xor(psum, 16);
        psum += __shfl_xor(psum, 32);

        const float cf = __expf(m_run - mnew);
        l_run = l_run * cf + psum;
        m_run = mnew;

        #pragma unroll
        for (int r = 0; r < 4; r++) {
            const float cfr = __shfl(cf, 4 * lg + r);
            #pragma unroll
            for (int h = 0; h < 4; h++) acc[h][r] *= cfr;
        }

        #pragma unroll
        for (int kb = 0; kb < 4; kb++)
            *(s16x4*)&Pl[w][lr][kb * 16 + lg * 4] = pq[kb];

        bf16x8 pa0 = *(const bf16x8*)&Pl[w][lr][lg * 8];
        bf16x8 pa1 = *(const bf16x8*)&Pl[w][lr][32 + lg * 8];

        #pragma unroll
        for (int h = 0; h < 4; h++) {
            bf16x8 b0 = *(const bf16x8*)&Vs[h * 16 + lr][lg * 8];
            bf16x8 b1 = *(const bf16x8*)&Vs[h * 16 + lr][32 + lg * 8];
            acc[h] = mfma16(pa0, b0, acc[h]);
            acc[h] = mfma16(pa1, b1, acc[h]);
        }
    }

    const float linv = 1.f / l_run;
    const int b_ = bh >> 4, hh = bh & 15;
    #pragma unroll
    for (int r = 0; r < 4; r++) {
        const float lv = __shfl(linv, 4 * lg + r);
        const int s = qt * 64 + w * 16 + 4 * lg + r;
        const size_t ro = ((size_t)b_ * Sc + s) * Dc + (size_t)hh * HDc;
        #pragma unroll
        for (int h = 0; h < 4; h++)
            ctx[ro + h * 16 + lr] = f2bf(acc[h][r] * lv);
    }
}

extern "C" void kernel_launch(void* const* d_in, const int* in_sizes, int n_in,
                              void* d_out, int out_size, void* d_ws, size_t ws_size,
                              hipStream_t stream)
{
    const float* query = (const float*)d_in[0];
    const float* key   = (const float*)d_in[1];
    const float* value = (const float*)d_in[2];
    const float* Wq = (const float*)d_in[3];
    const float* bq = (const float*)d_in[4];
    const float* Wk = (const float*)d_in[5];
    const float* bk = (const float*)d_in[6];
    const float* Wv = (const float*)d_in[7];
    const float* bv = (const float*)d_in[8];
    const float* Wo = (const float*)d_in[9];
    const float* bo = (const float*)d_in[10];

    constexpr size_t W = 1048576, AE = 4194304;
    unsigned short* wqb = (unsigned short*)d_ws;
    unsigned short* wkb = wqb + W;
    unsigned short* wvb = wkb + W;
    unsigned short* wob = wvb + W;
    unsigned short* qb  = wob + W;      // bf16 activations
    unsigned short* kb  = qb + AE;
    unsigned short* vb  = kb + AE;
    unsigned short* Qh  = vb + AE;      // projected heads
    unsigned short* Kh  = Qh + AE;
    unsigned short* Vth = Kh + AE;
    unsigned short* cx  = qb;           // overlay: qb dead after qkv_gemm

    cvt_all<<<8192, 256, 0, stream>>>(query, key, value, Wq, Wk, Wv, Wo,
                                      qb, kb, vb, wqb, wkb, wvb, wob);
    qkv_gemm<<<768, 256, 0, stream>>>(qb, kb, vb, wqb, wkb, wvb,
                                      bq, bk, bv, Qh, Kh, Vth);
    attn_fwd<<<Bc * Hc * (Sc / 64), 256, 0, stream>>>(Qh, Kh, Vth, cx);
    out_gemm<<<256, 256, 0, stream>>>(cx, wob, bo, (float*)d_out);
}

// Round 4
// 152.380 us; speedup vs baseline: 1.7567x; 1.0840x over previous
//
#include <hip/hip_runtime.h>
#include <hip/hip_bf16.h>

#define DEVFN __device__ __forceinline__

typedef __attribute__((ext_vector_type(8))) short bf16x8;   // 8 bf16 = 4 VGPR
typedef __attribute__((ext_vector_type(4))) short s16x4;
typedef __attribute__((ext_vector_type(4))) float f32x4;

constexpr int Bc = 2, Sc = 2048, Dc = 1024, Hc = 16, HDc = 64;
constexpr float SCALEc = 0.125f;  // HD^-0.5
constexpr float LOG2E  = 1.44269504088896340736f;

DEVFN unsigned short f2bf(float f) {  // RNE fp32 -> bf16
    union { float f; unsigned int u; } x; x.f = f;
    return (unsigned short)((x.u + 0x7fffu + ((x.u >> 16) & 1u)) >> 16);
}

DEVFN f32x4 mfma16(bf16x8 a, bf16x8 b, f32x4 c) {
    return __builtin_amdgcn_mfma_f32_16x16x32_bf16(a, b, c, 0, 0, 0);
}

DEVFN void gload16(const void* g, void* l) {  // async global->LDS, dest = base + lane*16
    __builtin_amdgcn_global_load_lds((const __attribute__((address_space(1))) void*)g,
                                     (__attribute__((address_space(3))) void*)l, 16, 0, 0);
}

// ---- one streaming pass: fp32 -> bf16 for q,k,v + 4 weights ----
__global__ __launch_bounds__(256) void cvt_all(
    const float* __restrict__ q, const float* __restrict__ k, const float* __restrict__ v,
    const float* __restrict__ wq, const float* __restrict__ wk,
    const float* __restrict__ wv, const float* __restrict__ wo,
    unsigned short* __restrict__ qb, unsigned short* __restrict__ kb, unsigned short* __restrict__ vb,
    unsigned short* __restrict__ wqb, unsigned short* __restrict__ wkb,
    unsigned short* __restrict__ wvb, unsigned short* __restrict__ wob)
{
    const unsigned t = blockIdx.x * 256 + threadIdx.x;
    const float* s; unsigned short* d; unsigned local;
    if (t < (3u << 19)) {
        const unsigned which = t >> 19; local = t & ((1u << 19) - 1);
        s = which == 0 ? q : which == 1 ? k : v;
        d = which == 0 ? qb : which == 1 ? kb : vb;
    } else {
        const unsigned t2 = t - (3u << 19);
        const unsigned which = t2 >> 17; local = t2 & ((1u << 17) - 1);
        s = which == 0 ? wq : which == 1 ? wk : which == 2 ? wv : wo;
        d = which == 0 ? wqb : which == 1 ? wkb : which == 2 ? wvb : wob;
    }
    const size_t off = (size_t)local * 8;
    float4 v0 = *(const float4*)(s + off);
    float4 v1 = *(const float4*)(s + off + 4);
    unsigned short t8[8] = {f2bf(v0.x), f2bf(v0.y), f2bf(v0.z), f2bf(v0.w),
                            f2bf(v1.x), f2bf(v1.y), f2bf(v1.z), f2bf(v1.w)};
    *(uint4*)(d + off) = *(const uint4*)t8;
}

// ---- fused QKV projection, pure bf16, m97 structure. Q is pre-scaled by SCALE*log2e
// so attention can use exp2 directly. g<2: out [B,H,S,HD]; g==2: out [B,H,HD,S].
__global__ __launch_bounds__(256) void qkv_gemm(
    const unsigned short* __restrict__ Aq, const unsigned short* __restrict__ Ak,
    const unsigned short* __restrict__ Av,
    const unsigned short* __restrict__ Wqb, const unsigned short* __restrict__ Wkb,
    const unsigned short* __restrict__ Wvb,
    const float* __restrict__ bqp, const float* __restrict__ bkp, const float* __restrict__ bvp,
    unsigned short* __restrict__ Qo, unsigned short* __restrict__ Ko, unsigned short* __restrict__ Vto)
{
    __shared__ short As[128 * 32];
    __shared__ short Bs[128 * 32];

    const int g = blockIdx.x >> 8;
    const unsigned short* A  = g == 0 ? Aq  : g == 1 ? Ak  : Av;
    const unsigned short* Bw = g == 0 ? Wqb : g == 1 ? Wkb : Wvb;
    const float* bias = g == 0 ? bqp : g == 1 ? bkp : bvp;
    const float scale = g == 0 ? SCALEc * LOG2E : 1.0f;

    const int tid = threadIdx.x, lane = tid & 63, w = tid >> 6;
    const int lr = lane & 15, lg = lane >> 4;
    const int bid = blockIdx.x & 255;
    const int tm = bid & 31, tn = bid >> 5;
    const int wm = (w >> 1) * 64, wn = (w & 1) * 64;

    const int c0 = 2 * w, c1 = 2 * w + 1;
    const int r0 = c0 * 16 + (lane >> 2), r1 = c1 * 16 + (lane >> 2);
    const int sl0 = ((lane & 3) ^ ((r0 >> 1) & 3)) * 8, sl1 = ((lane & 3) ^ ((r1 >> 1) & 3)) * 8;
    const unsigned short* Ap0 = A  + (size_t)(tm * 128 + r0) * 1024 + sl0;
    const unsigned short* Ap1 = A  + (size_t)(tm * 128 + r1) * 1024 + sl1;
    const unsigned short* Bp0 = Bw + (size_t)(tn * 128 + r0) * 1024 + sl0;
    const unsigned short* Bp1 = Bw + (size_t)(tn * 128 + r1) * 1024 + sl1;
    short* AL0 = &As[c0 * 512]; short* AL1 = &As[c1 * 512];
    short* BL0 = &Bs[c0 * 512]; short* BL1 = &Bs[c1 * 512];

    f32x4 acc[4][4] = {};
    const int fread = (lr >> 1) & 3;

    for (int k0 = 0; k0 < 1024; k0 += 32) {
        __syncthreads();
        gload16(Ap0 + k0, AL0);
        gload16(Ap1 + k0, AL1);
        gload16(Bp0 + k0, BL0);
        gload16(Bp1 + k0, BL1);
        __syncthreads();

        bf16x8 af[4], bfv[4];
        #pragma unroll
        for (int m = 0; m < 4; m++) {
            const int row = wm + m * 16 + lr;
            af[m] = *(const bf16x8*)&As[row * 32 + (lg ^ fread) * 8];
        }
        #pragma unroll
        for (int n = 0; n < 4; n++) {
            const int row = wn + n * 16 + lr;
            bfv[n] = *(const bf16x8*)&Bs[row * 32 + (lg ^ fread) * 8];
        }
        #pragma unroll
        for (int m = 0; m < 4; m++)
            #pragma unroll
            for (int n = 0; n < 4; n++)
                acc[m][n] = mfma16(af[m], bfv[n], acc[m][n]);
    }

    if (g < 2) {
        unsigned short* Y = g == 0 ? Qo : Ko;
        #pragma unroll
        for (int n = 0; n < 4; n++) {
            const int col = tn * 128 + wn + n * 16 + lr;
            const float bv = bias[col];
            const int hh = col >> 6, hd = col & 63;
            #pragma unroll
            for (int m = 0; m < 4; m++) {
                const int row0 = tm * 128 + wm + m * 16 + lg * 4;
                const int b_ = row0 >> 11, sQ = row0 & 2047;
                #pragma unroll
                for (int r = 0; r < 4; r++) {
                    const float val = (acc[m][n][r] + bv) * scale;
                    Y[(((size_t)(b_ * Hc + hh)) * Sc + (sQ + r)) * HDc + hd] = f2bf(val);
                }
            }
        }
    } else {
        #pragma unroll
        for (int n = 0; n < 4; n++) {
            const int col = tn * 128 + wn + n * 16 + lr;
            const float bv = bias[col];
            const int hh = col >> 6, hd = col & 63;
            #pragma unroll
            for (int m = 0; m < 4; m++) {
                const int row0 = tm * 128 + wm + m * 16 + lg * 4;
                const int b_ = row0 >> 11, sQ = row0 & 2047;
                unsigned long long pk = 0;
                #pragma unroll
                for (int r = 0; r < 4; r++)
                    pk |= (unsigned long long)f2bf(acc[m][n][r] + bv) << (16 * r);
                *(unsigned long long*)&Vto[(((size_t)(b_ * Hc + hh)) * HDc + hd) * Sc + sQ] = pk;
            }
        }
    }
}

// ---- output projection ----
__global__ __launch_bounds__(256) void out_gemm(
    const unsigned short* __restrict__ Ab, const unsigned short* __restrict__ Bw,
    const float* __restrict__ bias, float* __restrict__ Y)
{
    __shared__ short As[128 * 32];
    __shared__ short Bs[128 * 32];
    const int tid = threadIdx.x, lane = tid & 63, w = tid >> 6;
    const int lr = lane & 15, lg = lane >> 4;
    const int tm = blockIdx.x & 31, tn = blockIdx.x >> 5;
    const int wm = (w >> 1) * 64, wn = (w & 1) * 64;

    const int c0 = 2 * w, c1 = 2 * w + 1;
    const int r0 = c0 * 16 + (lane >> 2), r1 = c1 * 16 + (lane >> 2);
    const int sl0 = ((lane & 3) ^ ((r0 >> 1) & 3)) * 8, sl1 = ((lane & 3) ^ ((r1 >> 1) & 3)) * 8;
    const unsigned short* Ap0 = Ab + (size_t)(tm * 128 + r0) * 1024 + sl0;
    const unsigned short* Ap1 = Ab + (size_t)(tm * 128 + r1) * 1024 + sl1;
    const unsigned short* Bp0 = Bw + (size_t)(tn * 128 + r0) * 1024 + sl0;
    const unsigned short* Bp1 = Bw + (size_t)(tn * 128 + r1) * 1024 + sl1;
    short* AL0 = &As[c0 * 512]; short* AL1 = &As[c1 * 512];
    short* BL0 = &Bs[c0 * 512]; short* BL1 = &Bs[c1 * 512];

    f32x4 acc[4][4] = {};
    const int fread = (lr >> 1) & 3;

    for (int k0 = 0; k0 < 1024; k0 += 32) {
        __syncthreads();
        gload16(Ap0 + k0, AL0);
        gload16(Ap1 + k0, AL1);
        gload16(Bp0 + k0, BL0);
        gload16(Bp1 + k0, BL1);
        __syncthreads();

        bf16x8 af[4], bfv[4];
        #pragma unroll
        for (int m = 0; m < 4; m++) {
            const int row = wm + m * 16 + lr;
            af[m] = *(const bf16x8*)&As[row * 32 + (lg ^ fread) * 8];
        }
        #pragma unroll
        for (int n = 0; n < 4; n++) {
            const int row = wn + n * 16 + lr;
            bfv[n] = *(const bf16x8*)&Bs[row * 32 + (lg ^ fread) * 8];
        }
        #pragma unroll
        for (int m = 0; m < 4; m++)
            #pragma unroll
            for (int n = 0; n < 4; n++)
                acc[m][n] = mfma16(af[m], bfv[n], acc[m][n]);
    }

    #pragma unroll
    for (int n = 0; n < 4; n++) {
        const int col = tn * 128 + wn + n * 16 + lr;
        const float bv = bias[col];
        #pragma unroll
        for (int m = 0; m < 4; m++) {
            const int row0 = tm * 128 + wm + m * 16 + lg * 4;
            #pragma unroll
            for (int r = 0; r < 4; r++)
                Y[(size_t)(row0 + r) * 1024 + col] = acc[m][n][r] + bv;
        }
    }
}

// ---- flash attention v3: XOR-swizzled LDS, counted-vmcnt double buffer, exp2 softmax.
// Q,K: bf16 [B,H,S,HD] (Q pre-scaled by SCALE*log2e); V: bf16 [B,H,HD,S].
__global__ __launch_bounds__(256) void attn_fwd(
    const unsigned short* __restrict__ Q, const unsigned short* __restrict__ Kg,
    const unsigned short* __restrict__ Vtg, unsigned short* __restrict__ ctx)
{
    __shared__ short Ks[2][4096];   // [buf][row*64 + swz-slot], row=k-local, 64 rows
    __shared__ short Vs[2][4096];   // [buf][row*64 + swz-slot], row=hd
    __shared__ short Pl[4096];      // 4 waves x 16 q x 64 k, 8B-swizzled

    const int tid = threadIdx.x, lane = tid & 63, w = tid >> 6;
    const int lr = lane & 15, lg = lane >> 4;

    // XCD-chunked swizzle: all 32 q-tiles of a head on one XCD (grid 1024 = 8*128)
    const int blk = blockIdx.x;
    const int bh = (blk & 7) * 4 + ((blk >> 3) >> 5);
    const int qt = (blk >> 3) & 31;

    const unsigned short* Qb = Q   + (size_t)bh * Sc * HDc;
    const unsigned short* Kb = Kg  + (size_t)bh * Sc * HDc;
    const unsigned short* Vb = Vtg + (size_t)bh * HDc * Sc;

    // Q B-fragments, hoisted
    const int qrow = qt * 64 + w * 16 + lr;
    bf16x8 qf0 = *(const bf16x8*)&Qb[(size_t)qrow * HDc + lg * 8];
    bf16x8 qf1 = *(const bf16x8*)&Qb[(size_t)qrow * HDc + 32 + lg * 8];

    // staging addressing: wave w covers rows w*16..w*16+15 (2 gloads of 8 rows each);
    // global source pre-swizzled so linear LDS holds slot' = slot ^ (row&7)
    const int srow  = w * 16 + (lane >> 3);
    const int sslot = ((lane & 7) ^ (lane >> 3)) * 8;
    const unsigned short* Kst = Kb + (size_t)srow * HDc + sslot;   // + kt*4096 (+512 for i=1)
    const unsigned short* Vst = Vb + (size_t)srow * Sc + sslot;    // + kt*64  (+8*Sc for i=1)

    // read-side swizzled slot offsets (row&7 == lr&7 for all our rows)
    const int sw  = lr & 7;
    const int sA0 = (lg ^ sw) * 8;          // k/hd 0..31 slot
    const int sA1 = ((lg + 4) ^ sw) * 8;    // k/hd 32..63 slot
    const int sw2 = sw << 1;                // P-store 8B-slot XOR
    const int pbase = w * 1024 + lr * 64;

    float m_run = -1e30f, l_run = 0.f;
    f32x4 acc[4];
    #pragma unroll
    for (int h = 0; h < 4; h++) acc[h] = (f32x4){0.f, 0.f, 0.f, 0.f};

    // prologue: stage tile 0 into buf 0
    gload16(Kst,            &Ks[0][w * 1024]);
    gload16(Kst + 512,      &Ks[0][w * 1024 + 512]);
    gload16(Vst,            &Vs[0][w * 1024]);
    gload16(Vst + 8 * Sc,   &Vs[0][w * 1024 + 512]);

    int cur = 0;
    for (int kt = 0; kt < 32; ++kt) {
        {   // stage next tile (clamped re-stage on last iter keeps vmcnt uniform)
            const int nxt = kt < 31 ? kt + 1 : 31;
            const unsigned short* kp = Kst + (size_t)nxt * 4096;
            const unsigned short* vp = Vst + nxt * 64;
            short* kl = &Ks[cur ^ 1][w * 1024];
            short* vl = &Vs[cur ^ 1][w * 1024];
            gload16(kp,           kl);
            gload16(kp + 512,     kl + 512);
            gload16(vp,           vl);
            gload16(vp + 8 * Sc,  vl + 512);
        }
        asm volatile("s_waitcnt vmcnt(4)" ::: "memory");   // current tile's 4 done
        __builtin_amdgcn_s_barrier();
        __builtin_amdgcn_sched_barrier(0);

        const short* Kc = Ks[cur];
        const short* Vc = Vs[cur];

        // S^T = K·Q^T  (C: row = k-local = 4*lg+r, col = q = lr)
        f32x4 sf[4];
        __builtin_amdgcn_s_setprio(1);
        #pragma unroll
        for (int kb = 0; kb < 4; kb++) {
            const int rb = (kb * 16 + lr) * 64;
            bf16x8 a0 = *(const bf16x8*)&Kc[rb + sA0];
            bf16x8 a1 = *(const bf16x8*)&Kc[rb + sA1];
            f32x4 c = {};
            c = mfma16(a0, qf0, c);
            c = mfma16(a1, qf1, c);
            sf[kb] = c;
        }
        __builtin_amdgcn_s_setprio(0);

        // online softmax (log2-domain; Q pre-scaled by SCALE*log2e)
        float tmax = -1e30f;
        #pragma unroll
        for (int kb = 0; kb < 4; kb++)
            #pragma unroll
            for (int r = 0; r < 4; r++) tmax = fmaxf(tmax, sf[kb][r]);
        tmax = fmaxf(tmax, __shfl_xor(tmax, 16));
        tmax = fmaxf(tmax, __shfl_xor(tmax, 32));
        const float mnew = fmaxf(m_run, tmax);

        float psum = 0.f;
        #pragma unroll
        for (int kb = 0; kb < 4; kb++) {
            const float e0 = __builtin_amdgcn_exp2f(sf[kb][0] - mnew);
            const float e1 = __builtin_amdgcn_exp2f(sf[kb][1] - mnew);
            const float e2 = __builtin_amdgcn_exp2f(sf[kb][2] - mnew);
            const float e3 = __builtin_amdgcn_exp2f(sf[kb][3] - mnew);
            psum += (e0 + e1) + (e2 + e3);
            unsigned int d0, d1;
            asm("v_cvt_pk_bf16_f32 %0, %1, %2" : "=v"(d0) : "v"(e0), "v"(e1));
            asm("v_cvt_pk_bf16_f32 %0, %1, %2" : "=v"(d1) : "v"(e2), "v"(e3));
            const int s8 = ((kb << 2) | lg) ^ sw2;
            *(unsigned long long*)&Pl[pbase + s8 * 4] =
                (unsigned long long)d0 | ((unsigned long long)d1 << 32);
        }
        psum += __shfl_xor(psum, 16);
        psum += __shfl_xor(psum, 32);

        const float cf = __builtin_amdgcn_exp2f(m_run - mnew);
        l_run = l_run * cf + psum;
        m_run = mnew;

        #pragma unroll
        for (int r = 0; r < 4; r++) {
            const float cfr = __shfl(cf, 4 * lg + r);
            #pragma unroll
            for (int h = 0; h < 4; h++) acc[h][r] *= cfr;
        }

        // PV: A = P[q][k] from swizzled Pl, B = V^T rows
        bf16x8 pa0 = *(const bf16x8*)&Pl[pbase + sA0];
        bf16x8 pa1 = *(const bf16x8*)&Pl[pbase + sA1];

        __builtin_amdgcn_s_setprio(1);
        #pragma unroll
        for (int h = 0; h < 4; h++) {
            const int rb = (h * 16 + lr) * 64;
            bf16x8 b0 = *(const bf16x8*)&Vc[rb + sA0];
            bf16x8 b1 = *(const bf16x8*)&Vc[rb + sA1];
            acc[h] = mfma16(pa0, b0, acc[h]);
            acc[h] = mfma16(pa1, b1, acc[h]);
        }
        __builtin_amdgcn_s_setprio(0);

        asm volatile("s_waitcnt lgkmcnt(0)" ::: "memory");  // all LDS reads landed
        __builtin_amdgcn_sched_barrier(0);
        __builtin_amdgcn_s_barrier();                        // safe to overwrite cur
        cur ^= 1;
    }
    asm volatile("s_waitcnt vmcnt(0)" ::: "memory");  // drain the clamped extra stage

    const float linv = 1.f / l_run;
    const int b_ = bh >> 4, hh = bh & 15;
    #pragma unroll
    for (int r = 0; r < 4; r++) {
        const float lv = __shfl(linv, 4 * lg + r);
        const int s = qt * 64 + w * 16 + 4 * lg + r;
        const size_t ro = ((size_t)b_ * Sc + s) * Dc + (size_t)hh * HDc;
        #pragma unroll
        for (int h = 0; h < 4; h++)
            ctx[ro + h * 16 + lr] = f2bf(acc[h][r] * lv);
    }
}

extern "C" void kernel_launch(void* const* d_in, const int* in_sizes, int n_in,
                              void* d_out, int out_size, void* d_ws, size_t ws_size,
                              hipStream_t stream)
{
    const float* query = (const float*)d_in[0];
    const float* key   = (const float*)d_in[1];
    const float* value = (const float*)d_in[2];
    const float* Wq = (const float*)d_in[3];
    const float* bq = (const float*)d_in[4];
    const float* Wk = (const float*)d_in[5];
    const float* bk = (const float*)d_in[6];
    const float* Wv = (const float*)d_in[7];
    const float* bv = (const float*)d_in[8];
    const float* Wo = (const float*)d_in[9];
    const float* bo = (const float*)d_in[10];

    constexpr size_t W = 1048576, AE = 4194304;
    unsigned short* wqb = (unsigned short*)d_ws;
    unsigned short* wkb = wqb + W;
    unsigned short* wvb = wkb + W;
    unsigned short* wob = wvb + W;
    unsigned short* qb  = wob + W;
    unsigned short* kb  = qb + AE;
    unsigned short* vb  = kb + AE;
    unsigned short* Qh  = vb + AE;
    unsigned short* Kh  = Qh + AE;
    unsigned short* Vth = Kh + AE;
    unsigned short* cx  = qb;           // overlay: qb dead after qkv_gemm

    cvt_all<<<8192, 256, 0, stream>>>(query, key, value, Wq, Wk, Wv, Wo,
                                      qb, kb, vb, wqb, wkb, wvb, wob);
    qkv_gemm<<<768, 256, 0, stream>>>(qb, kb, vb, wqb, wkb, wvb,
                                      bq, bk, bv, Qh, Kh, Vth);
    attn_fwd<<<Bc * Hc * (Sc / 64), 256, 0, stream>>>(Qh, Kh, Vth, cx);
    out_gemm<<<256, 256, 0, stream>>>(cx, wob, bo, (float*)d_out);
}

// Round 5
// 136.841 us; speedup vs baseline: 1.9562x; 1.1136x over previous
//
#include <hip/hip_runtime.h>
#include <hip/hip_bf16.h>

#define DEVFN __device__ __forceinline__

typedef __attribute__((ext_vector_type(8))) short bf16x8;   // 8 bf16 = 4 VGPR
typedef __attribute__((ext_vector_type(4))) short s16x4;
typedef __attribute__((ext_vector_type(4))) float f32x4;

constexpr int Bc = 2, Sc = 2048, Dc = 1024, Hc = 16, HDc = 64;
constexpr float SCALEc = 0.125f;  // HD^-0.5
constexpr float LOG2E  = 1.44269504088896340736f;

DEVFN unsigned short f2bf(float f) {  // RNE fp32 -> bf16
    union { float f; unsigned int u; } x; x.f = f;
    return (unsigned short)((x.u + 0x7fffu + ((x.u >> 16) & 1u)) >> 16);
}

DEVFN f32x4 mfma16(bf16x8 a, bf16x8 b, f32x4 c) {
    return __builtin_amdgcn_mfma_f32_16x16x32_bf16(a, b, c, 0, 0, 0);
}

DEVFN void gload16(const void* g, void* l) {  // async global->LDS, dest = base + lane*16
    __builtin_amdgcn_global_load_lds((const __attribute__((address_space(1))) void*)g,
                                     (__attribute__((address_space(3))) void*)l, 16, 0, 0);
}

// ---- one streaming pass: fp32 -> bf16 for q,k,v + 4 weights ----
__global__ __launch_bounds__(256) void cvt_all(
    const float* __restrict__ q, const float* __restrict__ k, const float* __restrict__ v,
    const float* __restrict__ wq, const float* __restrict__ wk,
    const float* __restrict__ wv, const float* __restrict__ wo,
    unsigned short* __restrict__ qb, unsigned short* __restrict__ kb, unsigned short* __restrict__ vb,
    unsigned short* __restrict__ wqb, unsigned short* __restrict__ wkb,
    unsigned short* __restrict__ wvb, unsigned short* __restrict__ wob)
{
    const unsigned t = blockIdx.x * 256 + threadIdx.x;
    const float* s; unsigned short* d; unsigned local;
    if (t < (3u << 19)) {
        const unsigned which = t >> 19; local = t & ((1u << 19) - 1);
        s = which == 0 ? q : which == 1 ? k : v;
        d = which == 0 ? qb : which == 1 ? kb : vb;
    } else {
        const unsigned t2 = t - (3u << 19);
        const unsigned which = t2 >> 17; local = t2 & ((1u << 17) - 1);
        s = which == 0 ? wq : which == 1 ? wk : which == 2 ? wv : wo;
        d = which == 0 ? wqb : which == 1 ? wkb : which == 2 ? wvb : wob;
    }
    const size_t off = (size_t)local * 8;
    float4 v0 = *(const float4*)(s + off);
    float4 v1 = *(const float4*)(s + off + 4);
    unsigned short t8[8] = {f2bf(v0.x), f2bf(v0.y), f2bf(v0.z), f2bf(v0.w),
                            f2bf(v1.x), f2bf(v1.y), f2bf(v1.z), f2bf(v1.w)};
    *(uint4*)(d + off) = *(const uint4*)t8;
}

// ---- fused QKV projection, pure bf16, m97 structure. Q is pre-scaled by SCALE*log2e
// so attention can use exp2 directly. g<2: out [B,H,S,HD]; g==2: out [B,H,HD,S].
__global__ __launch_bounds__(256) void qkv_gemm(
    const unsigned short* __restrict__ Aq, const unsigned short* __restrict__ Ak,
    const unsigned short* __restrict__ Av,
    const unsigned short* __restrict__ Wqb, const unsigned short* __restrict__ Wkb,
    const unsigned short* __restrict__ Wvb,
    const float* __restrict__ bqp, const float* __restrict__ bkp, const float* __restrict__ bvp,
    unsigned short* __restrict__ Qo, unsigned short* __restrict__ Ko, unsigned short* __restrict__ Vto)
{
    __shared__ short As[128 * 32];
    __shared__ short Bs[128 * 32];

    const int g = blockIdx.x >> 8;
    const unsigned short* A  = g == 0 ? Aq  : g == 1 ? Ak  : Av;
    const unsigned short* Bw = g == 0 ? Wqb : g == 1 ? Wkb : Wvb;
    const float* bias = g == 0 ? bqp : g == 1 ? bkp : bvp;
    const float scale = g == 0 ? SCALEc * LOG2E : 1.0f;

    const int tid = threadIdx.x, lane = tid & 63, w = tid >> 6;
    const int lr = lane & 15, lg = lane >> 4;
    const int bid = blockIdx.x & 255;
    const int tm = bid & 31, tn = bid >> 5;
    const int wm = (w >> 1) * 64, wn = (w & 1) * 64;

    const int c0 = 2 * w, c1 = 2 * w + 1;
    const int r0 = c0 * 16 + (lane >> 2), r1 = c1 * 16 + (lane >> 2);
    const int sl0 = ((lane & 3) ^ ((r0 >> 1) & 3)) * 8, sl1 = ((lane & 3) ^ ((r1 >> 1) & 3)) * 8;
    const unsigned short* Ap0 = A  + (size_t)(tm * 128 + r0) * 1024 + sl0;
    const unsigned short* Ap1 = A  + (size_t)(tm * 128 + r1) * 1024 + sl1;
    const unsigned short* Bp0 = Bw + (size_t)(tn * 128 + r0) * 1024 + sl0;
    const unsigned short* Bp1 = Bw + (size_t)(tn * 128 + r1) * 1024 + sl1;
    short* AL0 = &As[c0 * 512]; short* AL1 = &As[c1 * 512];
    short* BL0 = &Bs[c0 * 512]; short* BL1 = &Bs[c1 * 512];

    f32x4 acc[4][4] = {};
    const int fread = (lr >> 1) & 3;

    for (int k0 = 0; k0 < 1024; k0 += 32) {
        __syncthreads();
        gload16(Ap0 + k0, AL0);
        gload16(Ap1 + k0, AL1);
        gload16(Bp0 + k0, BL0);
        gload16(Bp1 + k0, BL1);
        __syncthreads();

        bf16x8 af[4], bfv[4];
        #pragma unroll
        for (int m = 0; m < 4; m++) {
            const int row = wm + m * 16 + lr;
            af[m] = *(const bf16x8*)&As[row * 32 + (lg ^ fread) * 8];
        }
        #pragma unroll
        for (int n = 0; n < 4; n++) {
            const int row = wn + n * 16 + lr;
            bfv[n] = *(const bf16x8*)&Bs[row * 32 + (lg ^ fread) * 8];
        }
        #pragma unroll
        for (int m = 0; m < 4; m++)
            #pragma unroll
            for (int n = 0; n < 4; n++)
                acc[m][n] = mfma16(af[m], bfv[n], acc[m][n]);
    }

    if (g < 2) {
        unsigned short* Y = g == 0 ? Qo : Ko;
        #pragma unroll
        for (int n = 0; n < 4; n++) {
            const int col = tn * 128 + wn + n * 16 + lr;
            const float bv = bias[col];
            const int hh = col >> 6, hd = col & 63;
            #pragma unroll
            for (int m = 0; m < 4; m++) {
                const int row0 = tm * 128 + wm + m * 16 + lg * 4;
                const int b_ = row0 >> 11, sQ = row0 & 2047;
                #pragma unroll
                for (int r = 0; r < 4; r++) {
                    const float val = (acc[m][n][r] + bv) * scale;
                    Y[(((size_t)(b_ * Hc + hh)) * Sc + (sQ + r)) * HDc + hd] = f2bf(val);
                }
            }
        }
    } else {
        #pragma unroll
        for (int n = 0; n < 4; n++) {
            const int col = tn * 128 + wn + n * 16 + lr;
            const float bv = bias[col];
            const int hh = col >> 6, hd = col & 63;
            #pragma unroll
            for (int m = 0; m < 4; m++) {
                const int row0 = tm * 128 + wm + m * 16 + lg * 4;
                const int b_ = row0 >> 11, sQ = row0 & 2047;
                unsigned long long pk = 0;
                #pragma unroll
                for (int r = 0; r < 4; r++)
                    pk |= (unsigned long long)f2bf(acc[m][n][r] + bv) << (16 * r);
                *(unsigned long long*)&Vto[(((size_t)(b_ * Hc + hh)) * HDc + hd) * Sc + sQ] = pk;
            }
        }
    }
}

// ---- output projection ----
__global__ __launch_bounds__(256) void out_gemm(
    const unsigned short* __restrict__ Ab, const unsigned short* __restrict__ Bw,
    const float* __restrict__ bias, float* __restrict__ Y)
{
    __shared__ short As[128 * 32];
    __shared__ short Bs[128 * 32];
    const int tid = threadIdx.x, lane = tid & 63, w = tid >> 6;
    const int lr = lane & 15, lg = lane >> 4;
    const int tm = blockIdx.x & 31, tn = blockIdx.x >> 5;
    const int wm = (w >> 1) * 64, wn = (w & 1) * 64;

    const int c0 = 2 * w, c1 = 2 * w + 1;
    const int r0 = c0 * 16 + (lane >> 2), r1 = c1 * 16 + (lane >> 2);
    const int sl0 = ((lane & 3) ^ ((r0 >> 1) & 3)) * 8, sl1 = ((lane & 3) ^ ((r1 >> 1) & 3)) * 8;
    const unsigned short* Ap0 = Ab + (size_t)(tm * 128 + r0) * 1024 + sl0;
    const unsigned short* Ap1 = Ab + (size_t)(tm * 128 + r1) * 1024 + sl1;
    const unsigned short* Bp0 = Bw + (size_t)(tn * 128 + r0) * 1024 + sl0;
    const unsigned short* Bp1 = Bw + (size_t)(tn * 128 + r1) * 1024 + sl1;
    short* AL0 = &As[c0 * 512]; short* AL1 = &As[c1 * 512];
    short* BL0 = &Bs[c0 * 512]; short* BL1 = &Bs[c1 * 512];

    f32x4 acc[4][4] = {};
    const int fread = (lr >> 1) & 3;

    for (int k0 = 0; k0 < 1024; k0 += 32) {
        __syncthreads();
        gload16(Ap0 + k0, AL0);
        gload16(Ap1 + k0, AL1);
        gload16(Bp0 + k0, BL0);
        gload16(Bp1 + k0, BL1);
        __syncthreads();

        bf16x8 af[4], bfv[4];
        #pragma unroll
        for (int m = 0; m < 4; m++) {
            const int row = wm + m * 16 + lr;
            af[m] = *(const bf16x8*)&As[row * 32 + (lg ^ fread) * 8];
        }
        #pragma unroll
        for (int n = 0; n < 4; n++) {
            const int row = wn + n * 16 + lr;
            bfv[n] = *(const bf16x8*)&Bs[row * 32 + (lg ^ fread) * 8];
        }
        #pragma unroll
        for (int m = 0; m < 4; m++)
            #pragma unroll
            for (int n = 0; n < 4; n++)
                acc[m][n] = mfma16(af[m], bfv[n], acc[m][n]);
    }

    #pragma unroll
    for (int n = 0; n < 4; n++) {
        const int col = tn * 128 + wn + n * 16 + lr;
        const float bv = bias[col];
        #pragma unroll
        for (int m = 0; m < 4; m++) {
            const int row0 = tm * 128 + wm + m * 16 + lg * 4;
            #pragma unroll
            for (int r = 0; r < 4; r++)
                Y[(size_t)(row0 + r) * 1024 + col] = acc[m][n][r] + bv;
        }
    }
}

// ---- flash attention v4: no-max softmax (scores bounded, exp2 domain), QBLK=32/wave,
// XOR-swizzled LDS, counted-vmcnt double buffer, deferred l-reduction.
// Q,K: bf16 [B,H,S,HD] (Q pre-scaled by SCALE*log2e); V: bf16 [B,H,HD,S].
__global__ __launch_bounds__(256) void attn_fwd(
    const unsigned short* __restrict__ Q, const unsigned short* __restrict__ Kg,
    const unsigned short* __restrict__ Vtg, unsigned short* __restrict__ ctx)
{
    __shared__ short Ks[2][4096];   // [buf][krow*64 + swz-slot]
    __shared__ short Vs[2][4096];   // [buf][hd*64 + swz-slot]
    __shared__ short Pl[8192];      // 4 waves x 32 q x 64 k, 8B-swizzled

    const int tid = threadIdx.x, lane = tid & 63, w = tid >> 6;
    const int lr = lane & 15, lg = lane >> 4;

    // XCD-chunked swizzle: 512 blocks = 8 XCD chunks x 64; each head's 16 q-tiles together
    const int blk = blockIdx.x;
    const int bh = (blk & 7) * 4 + ((blk >> 3) >> 4);
    const int qt = (blk >> 3) & 15;

    const unsigned short* Qb = Q   + (size_t)bh * Sc * HDc;
    const unsigned short* Kb = Kg  + (size_t)bh * Sc * HDc;
    const unsigned short* Vb = Vtg + (size_t)bh * HDc * Sc;

    // Q B-fragments for 2 q-sub-tiles (32 q rows per wave), hoisted
    const int qbase = qt * 128 + w * 32;
    bf16x8 qf[2][2];
    #pragma unroll
    for (int s = 0; s < 2; s++) {
        const size_t qr = (size_t)(qbase + s * 16 + lr) * HDc;
        qf[s][0] = *(const bf16x8*)&Qb[qr + lg * 8];
        qf[s][1] = *(const bf16x8*)&Qb[qr + 32 + lg * 8];
    }

    // staging: wave w stages K rows w*16..+15 and V rows (hd) w*16..+15;
    // global source pre-swizzled so linear LDS holds slot' = slot ^ (row&7)
    const int srow  = w * 16 + (lane >> 3);
    const int sslot = ((lane & 7) ^ (lane >> 3)) * 8;
    const unsigned short* Kst = Kb + (size_t)srow * HDc + sslot;
    const unsigned short* Vst = Vb + (size_t)srow * Sc + sslot;

    // read-side swizzled slot offsets (all accessed rows have row&7 == lr&7)
    const int sw  = lr & 7;
    const int sA0 = (lg ^ sw) * 8;
    const int sA1 = ((lg + 4) ^ sw) * 8;
    const int sw2 = sw << 1;
    const int pb0 = w * 2048 + lr * 64;          // sub 0 P row
    const int pb1 = pb0 + 16 * 64;               // sub 1 P row

    float lp0 = 0.f, lp1 = 0.f;                  // per-lane l partials (q = lr)
    f32x4 acc[2][4] = {};

    // prologue: stage tile 0 into buf 0
    gload16(Kst,          &Ks[0][w * 1024]);
    gload16(Kst + 512,    &Ks[0][w * 1024 + 512]);
    gload16(Vst,          &Vs[0][w * 1024]);
    gload16(Vst + 8 * Sc, &Vs[0][w * 1024 + 512]);

    int cur = 0;
    for (int kt = 0; kt < 32; ++kt) {
        {   // stage next tile (clamped re-stage on last iter keeps vmcnt uniform)
            const int nxt = kt < 31 ? kt + 1 : 31;
            const unsigned short* kp = Kst + (size_t)nxt * 4096;
            const unsigned short* vp = Vst + nxt * 64;
            short* kl = &Ks[cur ^ 1][w * 1024];
            short* vl = &Vs[cur ^ 1][w * 1024];
            gload16(kp,           kl);
            gload16(kp + 512,     kl + 512);
            gload16(vp,           vl);
            gload16(vp + 8 * Sc,  vl + 512);
        }
        asm volatile("s_waitcnt vmcnt(4)" ::: "memory");
        __builtin_amdgcn_s_barrier();
        __builtin_amdgcn_sched_barrier(0);

        const short* Kc = Ks[cur];
        const short* Vc = Vs[cur];

        // S^T = K·Q^T for both q-subs; K-frags reused
        f32x4 sf[2][4];
        __builtin_amdgcn_s_setprio(1);
        #pragma unroll
        for (int kb = 0; kb < 4; kb++) {
            const int rb = (kb * 16 + lr) * 64;
            bf16x8 a0 = *(const bf16x8*)&Kc[rb + sA0];
            bf16x8 a1 = *(const bf16x8*)&Kc[rb + sA1];
            #pragma unroll
            for (int s = 0; s < 2; s++) {
                f32x4 c = {};
                c = mfma16(a0, qf[s][0], c);
                c = mfma16(a1, qf[s][1], c);
                sf[s][kb] = c;
            }
        }
        __builtin_amdgcn_s_setprio(0);

        // no-max softmax: P = exp2(s~) directly (scores bounded ~|8|, fp32 headroom 2^127)
        #pragma unroll
        for (int s = 0; s < 2; s++) {
            const int pb = s == 0 ? pb0 : pb1;
            float lacc = 0.f;
            #pragma unroll
            for (int kb = 0; kb < 4; kb++) {
                const float e0 = __builtin_amdgcn_exp2f(sf[s][kb][0]);
                const float e1 = __builtin_amdgcn_exp2f(sf[s][kb][1]);
                const float e2 = __builtin_amdgcn_exp2f(sf[s][kb][2]);
                const float e3 = __builtin_amdgcn_exp2f(sf[s][kb][3]);
                lacc += (e0 + e1) + (e2 + e3);
                unsigned int d0, d1;
                asm("v_cvt_pk_bf16_f32 %0, %1, %2" : "=v"(d0) : "v"(e0), "v"(e1));
                asm("v_cvt_pk_bf16_f32 %0, %1, %2" : "=v"(d1) : "v"(e2), "v"(e3));
                const int s8 = ((kb << 2) | lg) ^ sw2;
                *(unsigned long long*)&Pl[pb + s8 * 4] =
                    (unsigned long long)d0 | ((unsigned long long)d1 << 32);
            }
            if (s == 0) lp0 += lacc; else lp1 += lacc;
        }

        // PV: P A-frags (own-wave region), V B-frags reused across subs
        bf16x8 pa[2][2];
        pa[0][0] = *(const bf16x8*)&Pl[pb0 + sA0];
        pa[0][1] = *(const bf16x8*)&Pl[pb0 + sA1];
        pa[1][0] = *(const bf16x8*)&Pl[pb1 + sA0];
        pa[1][1] = *(const bf16x8*)&Pl[pb1 + sA1];

        __builtin_amdgcn_s_setprio(1);
        #pragma unroll
        for (int h = 0; h < 4; h++) {
            const int rb = (h * 16 + lr) * 64;
            bf16x8 b0 = *(const bf16x8*)&Vc[rb + sA0];
            bf16x8 b1 = *(const bf16x8*)&Vc[rb + sA1];
            #pragma unroll
            for (int s = 0; s < 2; s++) {
                acc[s][h] = mfma16(pa[s][0], b0, acc[s][h]);
                acc[s][h] = mfma16(pa[s][1], b1, acc[s][h]);
            }
        }
        __builtin_amdgcn_s_setprio(0);

        asm volatile("s_waitcnt lgkmcnt(0)" ::: "memory");
        __builtin_amdgcn_sched_barrier(0);
        __builtin_amdgcn_s_barrier();
        cur ^= 1;
    }
    asm volatile("s_waitcnt vmcnt(0)" ::: "memory");

    const int b_ = bh >> 4, hh = bh & 15;
    #pragma unroll
    for (int s = 0; s < 2; s++) {
        float l = s == 0 ? lp0 : lp1;
        l += __shfl_xor(l, 16);
        l += __shfl_xor(l, 32);
        const float linv = 1.f / l;
        #pragma unroll
        for (int r = 0; r < 4; r++) {
            const float lv = __shfl(linv, 4 * lg + r);
            const int sq = qbase + s * 16 + 4 * lg + r;
            const size_t ro = ((size_t)b_ * Sc + sq) * Dc + (size_t)hh * HDc;
            #pragma unroll
            for (int h = 0; h < 4; h++)
                ctx[ro + h * 16 + lr] = f2bf(acc[s][h][r] * lv);
        }
    }
}

extern "C" void kernel_launch(void* const* d_in, const int* in_sizes, int n_in,
                              void* d_out, int out_size, void* d_ws, size_t ws_size,
                              hipStream_t stream)
{
    const float* query = (const float*)d_in[0];
    const float* key   = (const float*)d_in[1];
    const float* value = (const float*)d_in[2];
    const float* Wq = (const float*)d_in[3];
    const float* bq = (const float*)d_in[4];
    const float* Wk = (const float*)d_in[5];
    const float* bk = (const float*)d_in[6];
    const float* Wv = (const float*)d_in[7];
    const float* bv = (const float*)d_in[8];
    const float* Wo = (const float*)d_in[9];
    const float* bo = (const float*)d_in[10];

    constexpr size_t W = 1048576, AE = 4194304;
    unsigned short* wqb = (unsigned short*)d_ws;
    unsigned short* wkb = wqb + W;
    unsigned short* wvb = wkb + W;
    unsigned short* wob = wvb + W;
    unsigned short* qb  = wob + W;
    unsigned short* kb  = qb + AE;
    unsigned short* vb  = kb + AE;
    unsigned short* Qh  = vb + AE;
    unsigned short* Kh  = Qh + AE;
    unsigned short* Vth = Kh + AE;
    unsigned short* cx  = qb;           // overlay: qb dead after qkv_gemm

    cvt_all<<<8192, 256, 0, stream>>>(query, key, value, Wq, Wk, Wv, Wo,
                                      qb, kb, vb, wqb, wkb, wvb, wob);
    qkv_gemm<<<768, 256, 0, stream>>>(qb, kb, vb, wqb, wkb, wvb,
                                      bq, bk, bv, Qh, Kh, Vth);
    attn_fwd<<<Bc * Hc * (Sc / 128), 256, 0, stream>>>(Qh, Kh, Vth, cx);
    out_gemm<<<256, 256, 0, stream>>>(cx, wob, bo, (float*)d_out);
}

// Round 7
// 136.771 us; speedup vs baseline: 1.9572x; 1.0005x over previous
//
#include <hip/hip_runtime.h>
#include <hip/hip_bf16.h>

#define DEVFN __device__ __forceinline__

typedef __attribute__((ext_vector_type(8))) short bf16x8;   // 8 bf16 = 4 VGPR
typedef __attribute__((ext_vector_type(4))) float f32x4;
typedef __attribute__((ext_vector_type(16))) float f32x16;

constexpr int Bc = 2, Sc = 2048, Dc = 1024, Hc = 16, HDc = 64;
constexpr float SCALEc = 0.125f;  // HD^-0.5
constexpr float LOG2E  = 1.44269504088896340736f;

DEVFN unsigned short f2bf(float f) {  // RNE fp32 -> bf16
    union { float f; unsigned int u; } x; x.f = f;
    return (unsigned short)((x.u + 0x7fffu + ((x.u >> 16) & 1u)) >> 16);
}

DEVFN f32x4 mfma16(bf16x8 a, bf16x8 b, f32x4 c) {
    return __builtin_amdgcn_mfma_f32_16x16x32_bf16(a, b, c, 0, 0, 0);
}
DEVFN f32x16 mfma32(bf16x8 a, bf16x8 b, f32x16 c) {
    return __builtin_amdgcn_mfma_f32_32x32x16_bf16(a, b, c, 0, 0, 0);
}

DEVFN void gload16(const void* g, void* l) {  // async global->LDS, dest = base + lane*16
    __builtin_amdgcn_global_load_lds((const __attribute__((address_space(1))) void*)g,
                                     (__attribute__((address_space(3))) void*)l, 16, 0, 0);
}

// ---- one streaming pass: fp32 -> bf16 for q,k,v + 4 weights ----
__global__ __launch_bounds__(256) void cvt_all(
    const float* __restrict__ q, const float* __restrict__ k, const float* __restrict__ v,
    const float* __restrict__ wq, const float* __restrict__ wk,
    const float* __restrict__ wv, const float* __restrict__ wo,
    unsigned short* __restrict__ qb, unsigned short* __restrict__ kb, unsigned short* __restrict__ vb,
    unsigned short* __restrict__ wqb, unsigned short* __restrict__ wkb,
    unsigned short* __restrict__ wvb, unsigned short* __restrict__ wob)
{
    const unsigned t = blockIdx.x * 256 + threadIdx.x;
    const float* s; unsigned short* d; unsigned local;
    if (t < (3u << 19)) {
        const unsigned which = t >> 19; local = t & ((1u << 19) - 1);
        s = which == 0 ? q : which == 1 ? k : v;
        d = which == 0 ? qb : which == 1 ? kb : vb;
    } else {
        const unsigned t2 = t - (3u << 19);
        const unsigned which = t2 >> 17; local = t2 & ((1u << 17) - 1);
        s = which == 0 ? wq : which == 1 ? wk : which == 2 ? wv : wo;
        d = which == 0 ? wqb : which == 1 ? wkb : which == 2 ? wvb : wob;
    }
    const size_t off = (size_t)local * 8;
    float4 v0 = *(const float4*)(s + off);
    float4 v1 = *(const float4*)(s + off + 4);
    unsigned short t8[8] = {f2bf(v0.x), f2bf(v0.y), f2bf(v0.z), f2bf(v0.w),
                            f2bf(v1.x), f2bf(v1.y), f2bf(v1.z), f2bf(v1.w)};
    *(uint4*)(d + off) = *(const uint4*)t8;
}

// ---- fused QKV projection, pure bf16, m97 structure. Q pre-scaled by SCALE*log2e.
// g<2: out [B,H,S,HD]; g==2: out [B,H,HD,S].
__global__ __launch_bounds__(256) void qkv_gemm(
    const unsigned short* __restrict__ Aq, const unsigned short* __restrict__ Ak,
    const unsigned short* __restrict__ Av,
    const unsigned short* __restrict__ Wqb, const unsigned short* __restrict__ Wkb,
    const unsigned short* __restrict__ Wvb,
    const float* __restrict__ bqp, const float* __restrict__ bkp, const float* __restrict__ bvp,
    unsigned short* __restrict__ Qo, unsigned short* __restrict__ Ko, unsigned short* __restrict__ Vto)
{
    __shared__ short As[128 * 32];
    __shared__ short Bs[128 * 32];

    const int g = blockIdx.x >> 8;
    const unsigned short* A  = g == 0 ? Aq  : g == 1 ? Ak  : Av;
    const unsigned short* Bw = g == 0 ? Wqb : g == 1 ? Wkb : Wvb;
    const float* bias = g == 0 ? bqp : g == 1 ? bkp : bvp;
    const float scale = g == 0 ? SCALEc * LOG2E : 1.0f;

    const int tid = threadIdx.x, lane = tid & 63, w = tid >> 6;
    const int lr = lane & 15, lg = lane >> 4;
    const int bid = blockIdx.x & 255;
    const int tm = bid & 31, tn = bid >> 5;
    const int wm = (w >> 1) * 64, wn = (w & 1) * 64;

    const int c0 = 2 * w, c1 = 2 * w + 1;
    const int r0 = c0 * 16 + (lane >> 2), r1 = c1 * 16 + (lane >> 2);
    const int sl0 = ((lane & 3) ^ ((r0 >> 1) & 3)) * 8, sl1 = ((lane & 3) ^ ((r1 >> 1) & 3)) * 8;
    const unsigned short* Ap0 = A  + (size_t)(tm * 128 + r0) * 1024 + sl0;
    const unsigned short* Ap1 = A  + (size_t)(tm * 128 + r1) * 1024 + sl1;
    const unsigned short* Bp0 = Bw + (size_t)(tn * 128 + r0) * 1024 + sl0;
    const unsigned short* Bp1 = Bw + (size_t)(tn * 128 + r1) * 1024 + sl1;
    short* AL0 = &As[c0 * 512]; short* AL1 = &As[c1 * 512];
    short* BL0 = &Bs[c0 * 512]; short* BL1 = &Bs[c1 * 512];

    f32x4 acc[4][4] = {};
    const int fread = (lr >> 1) & 3;

    for (int k0 = 0; k0 < 1024; k0 += 32) {
        __syncthreads();
        gload16(Ap0 + k0, AL0);
        gload16(Ap1 + k0, AL1);
        gload16(Bp0 + k0, BL0);
        gload16(Bp1 + k0, BL1);
        __syncthreads();

        bf16x8 af[4], bfv[4];
        #pragma unroll
        for (int m = 0; m < 4; m++) {
            const int row = wm + m * 16 + lr;
            af[m] = *(const bf16x8*)&As[row * 32 + (lg ^ fread) * 8];
        }
        #pragma unroll
        for (int n = 0; n < 4; n++) {
            const int row = wn + n * 16 + lr;
            bfv[n] = *(const bf16x8*)&Bs[row * 32 + (lg ^ fread) * 8];
        }
        #pragma unroll
        for (int m = 0; m < 4; m++)
            #pragma unroll
            for (int n = 0; n < 4; n++)
                acc[m][n] = mfma16(af[m], bfv[n], acc[m][n]);
    }

    if (g < 2) {
        unsigned short* Y = g == 0 ? Qo : Ko;
        #pragma unroll
        for (int n = 0; n < 4; n++) {
            const int col = tn * 128 + wn + n * 16 + lr;
            const float bv = bias[col];
            const int hh = col >> 6, hd = col & 63;
            #pragma unroll
            for (int m = 0; m < 4; m++) {
                const int row0 = tm * 128 + wm + m * 16 + lg * 4;
                const int b_ = row0 >> 11, sQ = row0 & 2047;
                #pragma unroll
                for (int r = 0; r < 4; r++) {
                    const float val = (acc[m][n][r] + bv) * scale;
                    Y[(((size_t)(b_ * Hc + hh)) * Sc + (sQ + r)) * HDc + hd] = f2bf(val);
                }
            }
        }
    } else {
        #pragma unroll
        for (int n = 0; n < 4; n++) {
            const int col = tn * 128 + wn + n * 16 + lr;
            const float bv = bias[col];
            const int hh = col >> 6, hd = col & 63;
            #pragma unroll
            for (int m = 0; m < 4; m++) {
                const int row0 = tm * 128 + wm + m * 16 + lg * 4;
                const int b_ = row0 >> 11, sQ = row0 & 2047;
                unsigned long long pk = 0;
                #pragma unroll
                for (int r = 0; r < 4; r++)
                    pk |= (unsigned long long)f2bf(acc[m][n][r] + bv) << (16 * r);
                *(unsigned long long*)&Vto[(((size_t)(b_ * Hc + hh)) * HDc + hd) * Sc + sQ] = pk;
            }
        }
    }
}

// ---- output projection ----
__global__ __launch_bounds__(256) void out_gemm(
    const unsigned short* __restrict__ Ab, const unsigned short* __restrict__ Bw,
    const float* __restrict__ bias, float* __restrict__ Y)
{
    __shared__ short As[128 * 32];
    __shared__ short Bs[128 * 32];
    const int tid = threadIdx.x, lane = tid & 63, w = tid >> 6;
    const int lr = lane & 15, lg = lane >> 4;
    const int tm = blockIdx.x & 31, tn = blockIdx.x >> 5;
    const int wm = (w >> 1) * 64, wn = (w & 1) * 64;

    const int c0 = 2 * w, c1 = 2 * w + 1;
    const int r0 = c0 * 16 + (lane >> 2), r1 = c1 * 16 + (lane >> 2);
    const int sl0 = ((lane & 3) ^ ((r0 >> 1) & 3)) * 8, sl1 = ((lane & 3) ^ ((r1 >> 1) & 3)) * 8;
    const unsigned short* Ap0 = Ab + (size_t)(tm * 128 + r0) * 1024 + sl0;
    const unsigned short* Ap1 = Ab + (size_t)(tm * 128 + r1) * 1024 + sl1;
    const unsigned short* Bp0 = Bw + (size_t)(tn * 128 + r0) * 1024 + sl0;
    const unsigned short* Bp1 = Bw + (size_t)(tn * 128 + r1) * 1024 + sl1;
    short* AL0 = &As[c0 * 512]; short* AL1 = &As[c1 * 512];
    short* BL0 = &Bs[c0 * 512]; short* BL1 = &Bs[c1 * 512];

    f32x4 acc[4][4] = {};
    const int fread = (lr >> 1) & 3;

    for (int k0 = 0; k0 < 1024; k0 += 32) {
        __syncthreads();
        gload16(Ap0 + k0, AL0);
        gload16(Ap1 + k0, AL1);
        gload16(Bp0 + k0, BL0);
        gload16(Bp1 + k0, BL1);
        __syncthreads();

        bf16x8 af[4], bfv[4];
        #pragma unroll
        for (int m = 0; m < 4; m++) {
            const int row = wm + m * 16 + lr;
            af[m] = *(const bf16x8*)&As[row * 32 + (lg ^ fread) * 8];
        }
        #pragma unroll
        for (int n = 0; n < 4; n++) {
            const int row = wn + n * 16 + lr;
            bfv[n] = *(const bf16x8*)&Bs[row * 32 + (lg ^ fread) * 8];
        }
        #pragma unroll
        for (int m = 0; m < 4; m++)
            #pragma unroll
            for (int n = 0; n < 4; n++)
                acc[m][n] = mfma16(af[m], bfv[n], acc[m][n]);
    }

    #pragma unroll
    for (int n = 0; n < 4; n++) {
        const int col = tn * 128 + wn + n * 16 + lr;
        const float bv = bias[col];
        #pragma unroll
        for (int m = 0; m < 4; m++) {
            const int row0 = tm * 128 + wm + m * 16 + lg * 4;
            #pragma unroll
            for (int r = 0; r < 4; r++)
                Y[(size_t)(row0 + r) * 1024 + col] = acc[m][n][r] + bv;
        }
    }
}

// ---- flash attention v7: 32x32x16 MFMA; P stays in-lane (no cross-lane ops) and the
// PV B-operand (V) is gathered with matching k-order via 2x ds_read_b64 per fragment —
// correctness independent of the MFMA A/B k-convention and of permlane semantics.
// Q,K: bf16 [B,H,S,HD] (Q pre-scaled by SCALE*log2e); V: bf16 [B,H,HD,S].
__global__ __launch_bounds__(256) void attn_fwd(
    const unsigned short* __restrict__ Q, const unsigned short* __restrict__ Kg,
    const unsigned short* __restrict__ Vtg, unsigned short* __restrict__ ctx)
{
    __shared__ short Ks[2][4096];   // [buf][krow*64 + swz-slot]  (64 rows x 64 bf16)
    __shared__ short Vs[2][4096];   // [buf][hd*64  + swz-slot]

    const int tid = threadIdx.x, lane = tid & 63, w = tid >> 6;
    const int l31 = lane & 31, hi = lane >> 5;

    // XCD-chunked: 512 blocks = 8 chunks x 64; a head's 16 q-tiles stay together
    const int blk = blockIdx.x;
    const int bh = (blk & 7) * 4 + ((blk >> 3) >> 4);
    const int qt = (blk >> 3) & 15;

    const unsigned short* Qb = Q   + (size_t)bh * Sc * HDc;
    const unsigned short* Kb = Kg  + (size_t)bh * Sc * HDc;
    const unsigned short* Vb = Vtg + (size_t)bh * HDc * Sc;

    // Q B-frags: lane (col=q=l31, hi) holds Q[q][hd = 16*kk + 8*hi + e]
    const int qbase = qt * 128 + w * 32;
    bf16x8 qf[4];
    {
        const size_t qr = (size_t)(qbase + l31) * HDc + hi * 8;
        #pragma unroll
        for (int kk = 0; kk < 4; kk++)
            qf[kk] = *(const bf16x8*)&Qb[qr + kk * 16];
    }

    // staging: wave w stages 16 K rows and 16 V rows; global source pre-swizzled
    // so linear LDS dest holds slot' = slot ^ (row&7)
    const int srow  = w * 16 + (lane >> 3);
    const int sslot = ((lane & 7) ^ (lane >> 3)) * 8;
    const unsigned short* Kst = Kb + (size_t)srow * HDc + sslot;
    const unsigned short* Vst = Vb + (size_t)srow * Sc + sslot;

    const int swk = lane & 7;   // row&7 for all fragment rows this lane touches

    float lp = 0.f;             // per-lane l partial for q = l31
    f32x16 acc0 = {}, acc1 = {};   // ctx[q(regs)][hd tile 0 / 1]

    // prologue: stage tile 0 into buf 0
    gload16(Kst,          &Ks[0][w * 1024]);
    gload16(Kst + 512,    &Ks[0][w * 1024 + 512]);
    gload16(Vst,          &Vs[0][w * 1024]);
    gload16(Vst + 8 * Sc, &Vs[0][w * 1024 + 512]);

    int cur = 0;
    for (int kt = 0; kt < 32; ++kt) {
        {   // stage next tile (clamped re-stage on last iter keeps vmcnt uniform)
            const int nxt = kt < 31 ? kt + 1 : 31;
            const unsigned short* kp = Kst + (size_t)nxt * 4096;
            const unsigned short* vp = Vst + nxt * 64;
            short* kl = &Ks[cur ^ 1][w * 1024];
            short* vl = &Vs[cur ^ 1][w * 1024];
            gload16(kp,           kl);
            gload16(kp + 512,     kl + 512);
            gload16(vp,           vl);
            gload16(vp + 8 * Sc,  vl + 512);
        }
        asm volatile("s_waitcnt vmcnt(4)" ::: "memory");
        __builtin_amdgcn_s_barrier();
        __builtin_amdgcn_sched_barrier(0);

        const short* Kc = Ks[cur];
        const short* Vc = Vs[cur];

        // S^T = K·Q^T via 32x32x16: D col = q = l31, rows = k (regs).
        // sf0: k 0..31, sf1: k 32..63; accumulate over hd chunks kk.
        f32x16 sf0 = {}, sf1 = {};
        __builtin_amdgcn_s_setprio(1);
        #pragma unroll
        for (int kk = 0; kk < 4; kk++) {
            const int sl = ((2 * kk + hi) ^ swk) * 8;
            bf16x8 a0 = *(const bf16x8*)&Kc[l31 * 64 + sl];
            bf16x8 a1 = *(const bf16x8*)&Kc[(32 + l31) * 64 + sl];
            sf0 = mfma32(a0, qf[kk], sf0);
            sf1 = mfma32(a1, qf[kk], sf1);
        }
        __builtin_amdgcn_s_setprio(0);

        // no-max softmax: P = exp2(s~). C/D reg r -> k = (r&3) + 8*(r>>2) + 4*hi
        // (+32 for sf1). So pair j holds k = (pattern) + 4*hi: j=0:(0,1) j=1:(2,3)
        // j=2:(8,9) j=3:(10,11) j=4:(16,17) j=5:(18,19) j=6:(24,25) j=7:(26,27).
        unsigned int p0[8], p1[8];
        #pragma unroll
        for (int j = 0; j < 8; j++) {
            const float a0 = __builtin_amdgcn_exp2f(sf0[2 * j]);
            const float a1 = __builtin_amdgcn_exp2f(sf0[2 * j + 1]);
            const float b0 = __builtin_amdgcn_exp2f(sf1[2 * j]);
            const float b1 = __builtin_amdgcn_exp2f(sf1[2 * j + 1]);
            lp += (a0 + a1) + (b0 + b1);
            asm("v_cvt_pk_bf16_f32 %0, %1, %2" : "=v"(p0[j]) : "v"(a0), "v"(a1));
            asm("v_cvt_pk_bf16_f32 %0, %1, %2" : "=v"(p1[j]) : "v"(b0), "v"(b1));
        }

        // PV over 4 k-windows m (k in [16m,16m+16)). A-frag = lane's own 4 pairs:
        // element (hi,e) -> k = 16m + 4*hi + (e&3) + 8*(e>>2). B-frag gathers V rows
        // in the SAME order: two 4-row runs {16m+4hi..+3} and {16m+8+4hi..+3} via
        // ds_read_b64 each. k-convention cancels (both operands share placement).
        __builtin_amdgcn_s_setprio(1);
        #pragma unroll
        for (int m = 0; m < 4; m++) {
            const unsigned int* pw = (m < 2) ? &p0[(m & 1) * 4] : &p1[(m & 1) * 4];
            const int s1 = ((2 * m) ^ swk) * 8 + 4 * hi;       // shorts within row
            const int s2 = ((2 * m + 1) ^ swk) * 8 + 4 * hi;
            union { unsigned long long d[2]; bf16x8 v; } b0, b1;
            b0.d[0] = *(const unsigned long long*)&Vc[l31 * 64 + s1];
            b0.d[1] = *(const unsigned long long*)&Vc[l31 * 64 + s2];
            b1.d[0] = *(const unsigned long long*)&Vc[(32 + l31) * 64 + s1];
            b1.d[1] = *(const unsigned long long*)&Vc[(32 + l31) * 64 + s2];
            union { unsigned int u[4]; bf16x8 v; } af;
            af.u[0] = pw[0]; af.u[1] = pw[1]; af.u[2] = pw[2]; af.u[3] = pw[3];
            acc0 = mfma32(af.v, b0.v, acc0);
            acc1 = mfma32(af.v, b1.v, acc1);
        }
        __builtin_amdgcn_s_setprio(0);

        asm volatile("s_waitcnt lgkmcnt(0)" ::: "memory");
        __builtin_amdgcn_sched_barrier(0);
        __builtin_amdgcn_s_barrier();
        cur ^= 1;
    }
    asm volatile("s_waitcnt vmcnt(0)" ::: "memory");

    // epilogue: l(q) = lp(q,hi0)+lp(q,hi1); normalize + store
    lp += __shfl_xor(lp, 32);
    const float linv = 1.f / lp;
    const int b_ = bh >> 4, hh = bh & 15;
    #pragma unroll
    for (int r = 0; r < 16; r++) {
        const int qr = (r & 3) + 8 * (r >> 2) + 4 * hi;
        const float lv = __shfl(linv, qr);
        const int sq = qbase + qr;
        unsigned short* co = &ctx[((size_t)(b_ * Sc + sq)) * Dc + (size_t)hh * HDc + l31];
        co[0]  = f2bf(acc0[r] * lv);
        co[32] = f2bf(acc1[r] * lv);
    }
}

extern "C" void kernel_launch(void* const* d_in, const int* in_sizes, int n_in,
                              void* d_out, int out_size, void* d_ws, size_t ws_size,
                              hipStream_t stream)
{
    const float* query = (const float*)d_in[0];
    const float* key   = (const float*)d_in[1];
    const float* value = (const float*)d_in[2];
    const float* Wq = (const float*)d_in[3];
    const float* bq = (const float*)d_in[4];
    const float* Wk = (const float*)d_in[5];
    const float* bk = (const float*)d_in[6];
    const float* Wv = (const float*)d_in[7];
    const float* bv = (const float*)d_in[8];
    const float* Wo = (const float*)d_in[9];
    const float* bo = (const float*)d_in[10];

    constexpr size_t W = 1048576, AE = 4194304;
    unsigned short* wqb = (unsigned short*)d_ws;
    unsigned short* wkb = wqb + W;
    unsigned short* wvb = wkb + W;
    unsigned short* wob = wvb + W;
    unsigned short* qb  = wob + W;
    unsigned short* kb  = qb + AE;
    unsigned short* vb  = kb + AE;
    unsigned short* Qh  = vb + AE;
    unsigned short* Kh  = Qh + AE;
    unsigned short* Vth = Kh + AE;
    unsigned short* cx  = qb;           // overlay: qb dead after qkv_gemm

    cvt_all<<<8192, 256, 0, stream>>>(query, key, value, Wq, Wk, Wv, Wo,
                                      qb, kb, vb, wqb, wkb, wvb, wob);
    qkv_gemm<<<768, 256, 0, stream>>>(qb, kb, vb, wqb, wkb, wvb,
                                      bq, bk, bv, Qh, Kh, Vth);
    attn_fwd<<<Bc * Hc * (Sc / 128), 256, 0, stream>>>(Qh, Kh, Vth, cx);
    out_gemm<<<256, 256, 0, stream>>>(cx, wob, bo, (float*)d_out);
}

// Round 9
// 135.494 us; speedup vs baseline: 1.9757x; 1.0094x over previous
//
#include <hip/hip_runtime.h>
#include <hip/hip_bf16.h>

#define DEVFN __device__ __forceinline__

typedef __attribute__((ext_vector_type(8))) short bf16x8;   // 8 bf16 = 4 VGPR
typedef __attribute__((ext_vector_type(4))) float f32x4;
typedef __attribute__((ext_vector_type(16))) float f32x16;

constexpr int Bc = 2, Sc = 2048, Dc = 1024, Hc = 16, HDc = 64;
constexpr float SCALEc = 0.125f;  // HD^-0.5
constexpr float LOG2E  = 1.44269504088896340736f;

DEVFN unsigned short f2bf(float f) {  // RNE fp32 -> bf16
    union { float f; unsigned int u; } x; x.f = f;
    return (unsigned short)((x.u + 0x7fffu + ((x.u >> 16) & 1u)) >> 16);
}

DEVFN f32x4 mfma16(bf16x8 a, bf16x8 b, f32x4 c) {
    return __builtin_amdgcn_mfma_f32_16x16x32_bf16(a, b, c, 0, 0, 0);
}
DEVFN f32x16 mfma32(bf16x8 a, bf16x8 b, f32x16 c) {
    return __builtin_amdgcn_mfma_f32_32x32x16_bf16(a, b, c, 0, 0, 0);
}

DEVFN void gload16(const void* g, void* l) {  // async global->LDS, dest = base + lane*16
    __builtin_amdgcn_global_load_lds((const __attribute__((address_space(1))) void*)g,
                                     (__attribute__((address_space(3))) void*)l, 16, 0, 0);
}

// ---- one streaming pass: fp32 -> bf16 for q,k,v + 4 weights ----
__global__ __launch_bounds__(256) void cvt_all(
    const float* __restrict__ q, const float* __restrict__ k, const float* __restrict__ v,
    const float* __restrict__ wq, const float* __restrict__ wk,
    const float* __restrict__ wv, const float* __restrict__ wo,
    unsigned short* __restrict__ qb, unsigned short* __restrict__ kb, unsigned short* __restrict__ vb,
    unsigned short* __restrict__ wqb, unsigned short* __restrict__ wkb,
    unsigned short* __restrict__ wvb, unsigned short* __restrict__ wob)
{
    const unsigned t = blockIdx.x * 256 + threadIdx.x;
    const float* s; unsigned short* d; unsigned local;
    if (t < (3u << 19)) {
        const unsigned which = t >> 19; local = t & ((1u << 19) - 1);
        s = which == 0 ? q : which == 1 ? k : v;
        d = which == 0 ? qb : which == 1 ? kb : vb;
    } else {
        const unsigned t2 = t - (3u << 19);
        const unsigned which = t2 >> 17; local = t2 & ((1u << 17) - 1);
        s = which == 0 ? wq : which == 1 ? wk : which == 2 ? wv : wo;
        d = which == 0 ? wqb : which == 1 ? wkb : which == 2 ? wvb : wob;
    }
    const size_t off = (size_t)local * 8;
    float4 v0 = *(const float4*)(s + off);
    float4 v1 = *(const float4*)(s + off + 4);
    unsigned short t8[8] = {f2bf(v0.x), f2bf(v0.y), f2bf(v0.z), f2bf(v0.w),
                            f2bf(v1.x), f2bf(v1.y), f2bf(v1.z), f2bf(v1.w)};
    *(uint4*)(d + off) = *(const uint4*)t8;
}

// ---- fused QKV projection, pure bf16, m97 structure. Q pre-scaled by SCALE*log2e.
// g<2: out [B,H,S,HD]; g==2: out [B,H,HD,S].
__global__ __launch_bounds__(256) void qkv_gemm(
    const unsigned short* __restrict__ Aq, const unsigned short* __restrict__ Ak,
    const unsigned short* __restrict__ Av,
    const unsigned short* __restrict__ Wqb, const unsigned short* __restrict__ Wkb,
    const unsigned short* __restrict__ Wvb,
    const float* __restrict__ bqp, const float* __restrict__ bkp, const float* __restrict__ bvp,
    unsigned short* __restrict__ Qo, unsigned short* __restrict__ Ko, unsigned short* __restrict__ Vto)
{
    __shared__ short As[128 * 32];
    __shared__ short Bs[128 * 32];

    const int g = blockIdx.x >> 8;
    const unsigned short* A  = g == 0 ? Aq  : g == 1 ? Ak  : Av;
    const unsigned short* Bw = g == 0 ? Wqb : g == 1 ? Wkb : Wvb;
    const float* bias = g == 0 ? bqp : g == 1 ? bkp : bvp;
    const float scale = g == 0 ? SCALEc * LOG2E : 1.0f;

    const int tid = threadIdx.x, lane = tid & 63, w = tid >> 6;
    const int lr = lane & 15, lg = lane >> 4;
    const int bid = blockIdx.x & 255;
    const int tm = bid & 31, tn = bid >> 5;
    const int wm = (w >> 1) * 64, wn = (w & 1) * 64;

    const int c0 = 2 * w, c1 = 2 * w + 1;
    const int r0 = c0 * 16 + (lane >> 2), r1 = c1 * 16 + (lane >> 2);
    const int sl0 = ((lane & 3) ^ ((r0 >> 1) & 3)) * 8, sl1 = ((lane & 3) ^ ((r1 >> 1) & 3)) * 8;
    const unsigned short* Ap0 = A  + (size_t)(tm * 128 + r0) * 1024 + sl0;
    const unsigned short* Ap1 = A  + (size_t)(tm * 128 + r1) * 1024 + sl1;
    const unsigned short* Bp0 = Bw + (size_t)(tn * 128 + r0) * 1024 + sl0;
    const unsigned short* Bp1 = Bw + (size_t)(tn * 128 + r1) * 1024 + sl1;
    short* AL0 = &As[c0 * 512]; short* AL1 = &As[c1 * 512];
    short* BL0 = &Bs[c0 * 512]; short* BL1 = &Bs[c1 * 512];

    f32x4 acc[4][4] = {};
    const int fread = (lr >> 1) & 3;

    for (int k0 = 0; k0 < 1024; k0 += 32) {
        __syncthreads();
        gload16(Ap0 + k0, AL0);
        gload16(Ap1 + k0, AL1);
        gload16(Bp0 + k0, BL0);
        gload16(Bp1 + k0, BL1);
        __syncthreads();

        bf16x8 af[4], bfv[4];
        #pragma unroll
        for (int m = 0; m < 4; m++) {
            const int row = wm + m * 16 + lr;
            af[m] = *(const bf16x8*)&As[row * 32 + (lg ^ fread) * 8];
        }
        #pragma unroll
        for (int n = 0; n < 4; n++) {
            const int row = wn + n * 16 + lr;
            bfv[n] = *(const bf16x8*)&Bs[row * 32 + (lg ^ fread) * 8];
        }
        #pragma unroll
        for (int m = 0; m < 4; m++)
            #pragma unroll
            for (int n = 0; n < 4; n++)
                acc[m][n] = mfma16(af[m], bfv[n], acc[m][n]);
    }

    if (g < 2) {
        unsigned short* Y = g == 0 ? Qo : Ko;
        #pragma unroll
        for (int n = 0; n < 4; n++) {
            const int col = tn * 128 + wn + n * 16 + lr;
            const float bv = bias[col];
            const int hh = col >> 6, hd = col & 63;
            #pragma unroll
            for (int m = 0; m < 4; m++) {
                const int row0 = tm * 128 + wm + m * 16 + lg * 4;
                const int b_ = row0 >> 11, sQ = row0 & 2047;
                #pragma unroll
                for (int r = 0; r < 4; r++) {
                    const float val = (acc[m][n][r] + bv) * scale;
                    Y[(((size_t)(b_ * Hc + hh)) * Sc + (sQ + r)) * HDc + hd] = f2bf(val);
                }
            }
        }
    } else {
        #pragma unroll
        for (int n = 0; n < 4; n++) {
            const int col = tn * 128 + wn + n * 16 + lr;
            const float bv = bias[col];
            const int hh = col >> 6, hd = col & 63;
            #pragma unroll
            for (int m = 0; m < 4; m++) {
                const int row0 = tm * 128 + wm + m * 16 + lg * 4;
                const int b_ = row0 >> 11, sQ = row0 & 2047;
                unsigned long long pk = 0;
                #pragma unroll
                for (int r = 0; r < 4; r++)
                    pk |= (unsigned long long)f2bf(acc[m][n][r] + bv) << (16 * r);
                *(unsigned long long*)&Vto[(((size_t)(b_ * Hc + hh)) * HDc + hd) * Sc + sQ] = pk;
            }
        }
    }
}

// ---- output projection ----
__global__ __launch_bounds__(256) void out_gemm(
    const unsigned short* __restrict__ Ab, const unsigned short* __restrict__ Bw,
    const float* __restrict__ bias, float* __restrict__ Y)
{
    __shared__ short As[128 * 32];
    __shared__ short Bs[128 * 32];
    const int tid = threadIdx.x, lane = tid & 63, w = tid >> 6;
    const int lr = lane & 15, lg = lane >> 4;
    const int tm = blockIdx.x & 31, tn = blockIdx.x >> 5;
    const int wm = (w >> 1) * 64, wn = (w & 1) * 64;

    const int c0 = 2 * w, c1 = 2 * w + 1;
    const int r0 = c0 * 16 + (lane >> 2), r1 = c1 * 16 + (lane >> 2);
    const int sl0 = ((lane & 3) ^ ((r0 >> 1) & 3)) * 8, sl1 = ((lane & 3) ^ ((r1 >> 1) & 3)) * 8;
    const unsigned short* Ap0 = Ab + (size_t)(tm * 128 + r0) * 1024 + sl0;
    const unsigned short* Ap1 = Ab + (size_t)(tm * 128 + r1) * 1024 + sl1;
    const unsigned short* Bp0 = Bw + (size_t)(tn * 128 + r0) * 1024 + sl0;
    const unsigned short* Bp1 = Bw + (size_t)(tn * 128 + r1) * 1024 + sl1;
    short* AL0 = &As[c0 * 512]; short* AL1 = &As[c1 * 512];
    short* BL0 = &Bs[c0 * 512]; short* BL1 = &Bs[c1 * 512];

    f32x4 acc[4][4] = {};
    const int fread = (lr >> 1) & 3;

    for (int k0 = 0; k0 < 1024; k0 += 32) {
        __syncthreads();
        gload16(Ap0 + k0, AL0);
        gload16(Ap1 + k0, AL1);
        gload16(Bp0 + k0, BL0);
        gload16(Bp1 + k0, BL1);
        __syncthreads();

        bf16x8 af[4], bfv[4];
        #pragma unroll
        for (int m = 0; m < 4; m++) {
            const int row = wm + m * 16 + lr;
            af[m] = *(const bf16x8*)&As[row * 32 + (lg ^ fread) * 8];
        }
        #pragma unroll
        for (int n = 0; n < 4; n++) {
            const int row = wn + n * 16 + lr;
            bfv[n] = *(const bf16x8*)&Bs[row * 32 + (lg ^ fread) * 8];
        }
        #pragma unroll
        for (int m = 0; m < 4; m++)
            #pragma unroll
            for (int n = 0; n < 4; n++)
                acc[m][n] = mfma16(af[m], bfv[n], acc[m][n]);
    }

    #pragma unroll
    for (int n = 0; n < 4; n++) {
        const int col = tn * 128 + wn + n * 16 + lr;
        const float bv = bias[col];
        #pragma unroll
        for (int m = 0; m < 4; m++) {
            const int row0 = tm * 128 + wm + m * 16 + lg * 4;
            #pragma unroll
            for (int r = 0; r < 4; r++)
                Y[(size_t)(row0 + r) * 1024 + col] = acc[m][n][r] + bv;
        }
    }
}

// ---- flash attention v9: 8 waves/block (512 thr, grid 256 = 1 block/CU), 32x32x16
// MFMA, R7's convention-free in-lane P pairing (b64 V-gathers), accl ones-column MFMA
// for the softmax denominator, Z-hoisted QK init, no-max exp2 softmax, XOR-swizzled
// LDS, counted-vmcnt(2) double buffer.
// Q,K: bf16 [B,H,S,HD] (Q pre-scaled by SCALE*log2e); V: bf16 [B,H,HD,S].
__global__ __launch_bounds__(512, 2) void attn_fwd(
    const unsigned short* __restrict__ Q, const unsigned short* __restrict__ Kg,
    const unsigned short* __restrict__ Vtg, unsigned short* __restrict__ ctx)
{
    __shared__ short Ks[2][4096];   // [buf][krow*64 + swz-slot]  (64 rows x 64 bf16)
    __shared__ short Vs[2][4096];   // [buf][hd*64  + swz-slot]

    const int tid = threadIdx.x, lane = tid & 63, w = tid >> 6;   // w in 0..7
    const int l31 = lane & 31, hi = lane >> 5;

    // XCD-chunked: 256 blocks = 8 XCDs x 32; 4 heads per XCD, 8 q-tiles per head
    const int blk = blockIdx.x;
    const int idx = blk >> 3;
    const int bh = (blk & 7) * 4 + (idx >> 3);
    const int qt = idx & 7;

    const unsigned short* Qb = Q   + (size_t)bh * Sc * HDc;
    const unsigned short* Kb = Kg  + (size_t)bh * Sc * HDc;
    const unsigned short* Vb = Vtg + (size_t)bh * HDc * Sc;

    // Q B-frags: lane (col=q=l31, hi) holds Q[q][hd = 16*kk + 8*hi + e]
    const int qbase = qt * 256 + w * 32;
    bf16x8 qf[4];
    {
        const size_t qr = (size_t)(qbase + l31) * HDc + hi * 8;
        #pragma unroll
        for (int kk = 0; kk < 4; kk++)
            qf[kk] = *(const bf16x8*)&Qb[qr + kk * 16];
    }

    // staging: wave w stages 8 K rows + 8 V rows (64 lanes x 16B = 8 rows x 128B);
    // global source pre-swizzled so linear LDS dest holds slot' = slot ^ (row&7)
    const int srow  = w * 8 + (lane >> 3);
    const int sslot = ((lane & 7) ^ (lane >> 3)) * 8;
    const unsigned short* Kst = Kb + (size_t)srow * HDc + sslot;
    const unsigned short* Vst = Vb + (size_t)srow * Sc + sslot;

    const int swk = lane & 7;   // row&7 for all fragment rows this lane touches

    const f32x16 Z = {};
    f32x16 acc0 = {}, acc1 = {}, accl = {};   // ctx hd-tiles 0/1 + denominator l

    union { unsigned int u[4]; bf16x8 v; } ones;
    ones.u[0] = ones.u[1] = ones.u[2] = ones.u[3] = 0x3F803F80u;  // bf16 1.0 x8

    // prologue: stage tile 0 into buf 0 (1 K-gload + 1 V-gload per lane)
    gload16(Kst, &Ks[0][w * 512]);
    gload16(Vst, &Vs[0][w * 512]);

    int cur = 0;
    for (int kt = 0; kt < 32; ++kt) {
        {   // stage next tile (clamped re-stage on last iter keeps vmcnt uniform)
            const int nxt = kt < 31 ? kt + 1 : 31;
            gload16(Kst + (size_t)nxt * 4096, &Ks[cur ^ 1][w * 512]);
            gload16(Vst + nxt * 64,           &Vs[cur ^ 1][w * 512]);
        }
        asm volatile("s_waitcnt vmcnt(2)" ::: "memory");   // current tile's 2 done
        __builtin_amdgcn_s_barrier();
        __builtin_amdgcn_sched_barrier(0);

        const short* Kc = Ks[cur];
        const short* Vc = Vs[cur];

        // S^T = K·Q^T via 32x32x16: D col = q = l31, rows = k (regs).
        f32x16 sf0, sf1;
        __builtin_amdgcn_s_setprio(1);
        {
            const int sl = (hi ^ swk) * 8;
            bf16x8 a0 = *(const bf16x8*)&Kc[l31 * 64 + sl];
            bf16x8 a1 = *(const bf16x8*)&Kc[(32 + l31) * 64 + sl];
            sf0 = mfma32(a0, qf[0], Z);
            sf1 = mfma32(a1, qf[0], Z);
        }
        #pragma unroll
        for (int kk = 1; kk < 4; kk++) {
            const int sl = ((2 * kk + hi) ^ swk) * 8;
            bf16x8 a0 = *(const bf16x8*)&Kc[l31 * 64 + sl];
            bf16x8 a1 = *(const bf16x8*)&Kc[(32 + l31) * 64 + sl];
            sf0 = mfma32(a0, qf[kk], sf0);
            sf1 = mfma32(a1, qf[kk], sf1);
        }
        __builtin_amdgcn_s_setprio(0);

        // no-max softmax: P = exp2(s~). C/D reg r -> k = (r&3) + 8*(r>>2) + 4*hi
        // pair j packs regs (2j, 2j+1): j0:(k0,k1) j1:(k2,k3) j2:(k8,k9) j3:(k10,k11)
        // j4:(k16,k17) j5:(k18,k19) j6:(k24,k25) j7:(k26,k27)   (all +4hi; p1 = +32)
        unsigned int p0[8], p1[8];
        #pragma unroll
        for (int j = 0; j < 8; j++) {
            const float a0 = __builtin_amdgcn_exp2f(sf0[2 * j]);
            const float a1 = __builtin_amdgcn_exp2f(sf0[2 * j + 1]);
            const float b0 = __builtin_amdgcn_exp2f(sf1[2 * j]);
            const float b1 = __builtin_amdgcn_exp2f(sf1[2 * j + 1]);
            asm("v_cvt_pk_bf16_f32 %0, %1, %2" : "=v"(p0[j]) : "v"(a0), "v"(a1));
            asm("v_cvt_pk_bf16_f32 %0, %1, %2" : "=v"(p1[j]) : "v"(b0), "v"(b1));
        }

        // PV over 4 k-windows m (k in [16m,16m+16)). A-frag = lane's own 4 pairs:
        // element (hi,e) -> k = 16m + 4*hi + (e&3) + 8*(e>>2). B-frag gathers V rows
        // in the SAME order via 2x ds_read_b64 per fragment (k-convention cancels).
        // accl accumulates the full window row-sum l via B = ones (MFMA contracts
        // both hi halves, so accl needs no cross-lane reduce).
        __builtin_amdgcn_s_setprio(1);
        #pragma unroll
        for (int m = 0; m < 4; m++) {
            const unsigned int* pw = (m < 2) ? &p0[(m & 1) * 4] : &p1[(m & 1) * 4];
            const int s1 = ((2 * m) ^ swk) * 8 + 4 * hi;       // shorts within row
            const int s2 = ((2 * m + 1) ^ swk) * 8 + 4 * hi;
            union { unsigned long long d[2]; bf16x8 v; } b0, b1;
            b0.d[0] = *(const unsigned long long*)&Vc[l31 * 64 + s1];
            b0.d[1] = *(const unsigned long long*)&Vc[l31 * 64 + s2];
            b1.d[0] = *(const unsigned long long*)&Vc[(32 + l31) * 64 + s1];
            b1.d[1] = *(const unsigned long long*)&Vc[(32 + l31) * 64 + s2];
            union { unsigned int u[4]; bf16x8 v; } af;
            af.u[0] = pw[0]; af.u[1] = pw[1]; af.u[2] = pw[2]; af.u[3] = pw[3];
            acc0 = mfma32(af.v, b0.v, acc0);
            acc1 = mfma32(af.v, b1.v, acc1);
            accl = mfma32(af.v, ones.v, accl);
        }
        __builtin_amdgcn_s_setprio(0);

        asm volatile("s_waitcnt lgkmcnt(0)" ::: "memory");
        __builtin_amdgcn_sched_barrier(0);
        __builtin_amdgcn_s_barrier();
        cur ^= 1;
    }
    asm volatile("s_waitcnt vmcnt(0)" ::: "memory");

    // epilogue: lane holds l(q) in accl[r] (all cols equal); rcp + store
    const int b_ = bh >> 4, hh = bh & 15;
    #pragma unroll
    for (int r = 0; r < 16; r++) {
        const int qr = (r & 3) + 8 * (r >> 2) + 4 * hi;
        const float lv = __builtin_amdgcn_rcpf(accl[r]);
        const int sq = qbase + qr;
        unsigned short* co = &ctx[((size_t)(b_ * Sc + sq)) * Dc + (size_t)hh * HDc + l31];
        co[0]  = f2bf(acc0[r] * lv);
        co[32] = f2bf(acc1[r] * lv);
    }
}

extern "C" void kernel_launch(void* const* d_in, const int* in_sizes, int n_in,
                              void* d_out, int out_size, void* d_ws, size_t ws_size,
                              hipStream_t stream)
{
    const float* query = (const float*)d_in[0];
    const float* key   = (const float*)d_in[1];
    const float* value = (const float*)d_in[2];
    const float* Wq = (const float*)d_in[3];
    const float* bq = (const float*)d_in[4];
    const float* Wk = (const float*)d_in[5];
    const float* bk = (const float*)d_in[6];
    const float* Wv = (const float*)d_in[7];
    const float* bv = (const float*)d_in[8];
    const float* Wo = (const float*)d_in[9];
    const float* bo = (const float*)d_in[10];

    constexpr size_t W = 1048576, AE = 4194304;
    unsigned short* wqb = (unsigned short*)d_ws;
    unsigned short* wkb = wqb + W;
    unsigned short* wvb = wkb + W;
    unsigned short* wob = wvb + W;
    unsigned short* qb  = wob + W;
    unsigned short* kb  = qb + AE;
    unsigned short* vb  = kb + AE;
    unsigned short* Qh  = vb + AE;
    unsigned short* Kh  = Qh + AE;
    unsigned short* Vth = Kh + AE;
    unsigned short* cx  = qb;           // overlay: qb dead after qkv_gemm

    cvt_all<<<8192, 256, 0, stream>>>(query, key, value, Wq, Wk, Wv, Wo,
                                      qb, kb, vb, wqb, wkb, wvb, wob);
    qkv_gemm<<<768, 256, 0, stream>>>(qb, kb, vb, wqb, wkb, wvb,
                                      bq, bk, bv, Qh, Kh, Vth);
    attn_fwd<<<256, 512, 0, stream>>>(Qh, Kh, Vth, cx);
    out_gemm<<<256, 256, 0, stream>>>(cx, wob, bo, (float*)d_out);
}

// Round 10
// 131.046 us; speedup vs baseline: 2.0427x; 1.0339x over previous
//
#include <hip/hip_runtime.h>
#include <hip/hip_bf16.h>

#define DEVFN __device__ __forceinline__

typedef __attribute__((ext_vector_type(8))) short bf16x8;   // 8 bf16 = 4 VGPR
typedef __attribute__((ext_vector_type(4))) float f32x4;
typedef __attribute__((ext_vector_type(16))) float f32x16;

constexpr int Bc = 2, Sc = 2048, Dc = 1024, Hc = 16, HDc = 64;
constexpr float SCALEc = 0.125f;  // HD^-0.5
constexpr float LOG2E  = 1.44269504088896340736f;

DEVFN unsigned short f2bf(float f) {  // RNE fp32 -> bf16
    union { float f; unsigned int u; } x; x.f = f;
    return (unsigned short)((x.u + 0x7fffu + ((x.u >> 16) & 1u)) >> 16);
}

DEVFN f32x4 mfma16(bf16x8 a, bf16x8 b, f32x4 c) {
    return __builtin_amdgcn_mfma_f32_16x16x32_bf16(a, b, c, 0, 0, 0);
}
DEVFN f32x16 mfma32(bf16x8 a, bf16x8 b, f32x16 c) {
    return __builtin_amdgcn_mfma_f32_32x32x16_bf16(a, b, c, 0, 0, 0);
}

DEVFN void gload16(const void* g, void* l) {  // async global->LDS, dest = base + lane*16
    __builtin_amdgcn_global_load_lds((const __attribute__((address_space(1))) void*)g,
                                     (__attribute__((address_space(3))) void*)l, 16, 0, 0);
}

// ---- one streaming pass: fp32 -> bf16 for q,k,v + 4 weights ----
__global__ __launch_bounds__(256) void cvt_all(
    const float* __restrict__ q, const float* __restrict__ k, const float* __restrict__ v,
    const float* __restrict__ wq, const float* __restrict__ wk,
    const float* __restrict__ wv, const float* __restrict__ wo,
    unsigned short* __restrict__ qb, unsigned short* __restrict__ kb, unsigned short* __restrict__ vb,
    unsigned short* __restrict__ wqb, unsigned short* __restrict__ wkb,
    unsigned short* __restrict__ wvb, unsigned short* __restrict__ wob)
{
    const unsigned t = blockIdx.x * 256 + threadIdx.x;
    const float* s; unsigned short* d; unsigned local;
    if (t < (3u << 19)) {
        const unsigned which = t >> 19; local = t & ((1u << 19) - 1);
        s = which == 0 ? q : which == 1 ? k : v;
        d = which == 0 ? qb : which == 1 ? kb : vb;
    } else {
        const unsigned t2 = t - (3u << 19);
        const unsigned which = t2 >> 17; local = t2 & ((1u << 17) - 1);
        s = which == 0 ? wq : which == 1 ? wk : which == 2 ? wv : wo;
        d = which == 0 ? wqb : which == 1 ? wkb : which == 2 ? wvb : wob;
    }
    const size_t off = (size_t)local * 8;
    float4 v0 = *(const float4*)(s + off);
    float4 v1 = *(const float4*)(s + off + 4);
    unsigned short t8[8] = {f2bf(v0.x), f2bf(v0.y), f2bf(v0.z), f2bf(v0.w),
                            f2bf(v1.x), f2bf(v1.y), f2bf(v1.z), f2bf(v1.w)};
    *(uint4*)(d + off) = *(const uint4*)t8;
}

// ---- fused QKV projection, pure bf16, dbuf + counted vmcnt. Q pre-scaled by SCALE*log2e.
// g<2: out [B,H,S,HD]; g==2: out [B,H,HD,S] with k-bits 2<->3 swapped inside each
// 16-row group (so attention's PV B-fragment is one conflict-free b128).
__global__ __launch_bounds__(256) void qkv_gemm(
    const unsigned short* __restrict__ Aq, const unsigned short* __restrict__ Ak,
    const unsigned short* __restrict__ Av,
    const unsigned short* __restrict__ Wqb, const unsigned short* __restrict__ Wkb,
    const unsigned short* __restrict__ Wvb,
    const float* __restrict__ bqp, const float* __restrict__ bkp, const float* __restrict__ bvp,
    unsigned short* __restrict__ Qo, unsigned short* __restrict__ Ko, unsigned short* __restrict__ Vto)
{
    __shared__ short As[2][4096];
    __shared__ short Bs[2][4096];

    const int g = blockIdx.x >> 8;
    const unsigned short* A  = g == 0 ? Aq  : g == 1 ? Ak  : Av;
    const unsigned short* Bw = g == 0 ? Wqb : g == 1 ? Wkb : Wvb;
    const float* bias = g == 0 ? bqp : g == 1 ? bkp : bvp;
    const float scale = g == 0 ? SCALEc * LOG2E : 1.0f;

    const int tid = threadIdx.x, lane = tid & 63, w = tid >> 6;
    const int lr = lane & 15, lg = lane >> 4;
    const int bid = blockIdx.x & 255;
    const int tm = bid & 31, tn = bid >> 5;
    const int wm = (w >> 1) * 64, wn = (w & 1) * 64;

    const int c0 = 2 * w, c1 = 2 * w + 1;
    const int r0 = c0 * 16 + (lane >> 2), r1 = c1 * 16 + (lane >> 2);
    const int sl0 = ((lane & 3) ^ ((r0 >> 1) & 3)) * 8, sl1 = ((lane & 3) ^ ((r1 >> 1) & 3)) * 8;
    const unsigned short* Ap0 = A  + (size_t)(tm * 128 + r0) * 1024 + sl0;
    const unsigned short* Ap1 = A  + (size_t)(tm * 128 + r1) * 1024 + sl1;
    const unsigned short* Bp0 = Bw + (size_t)(tn * 128 + r0) * 1024 + sl0;
    const unsigned short* Bp1 = Bw + (size_t)(tn * 128 + r1) * 1024 + sl1;

    f32x4 acc[4][4] = {};
    const int fread = (lr >> 1) & 3;

    // prologue: stage tile 0 into buf 0
    gload16(Ap0, &As[0][c0 * 512]);
    gload16(Ap1, &As[0][c1 * 512]);
    gload16(Bp0, &Bs[0][c0 * 512]);
    gload16(Bp1, &Bs[0][c1 * 512]);

    int cur = 0;
    for (int k0 = 0; k0 < 1024; k0 += 32) {
        const int nk = (k0 + 32 < 1024) ? k0 + 32 : k0;   // clamped re-stage on last iter
        gload16(Ap0 + nk, &As[cur ^ 1][c0 * 512]);
        gload16(Ap1 + nk, &As[cur ^ 1][c1 * 512]);
        gload16(Bp0 + nk, &Bs[cur ^ 1][c0 * 512]);
        gload16(Bp1 + nk, &Bs[cur ^ 1][c1 * 512]);
        asm volatile("s_waitcnt vmcnt(4)" ::: "memory");   // current tile's 4 done
        __builtin_amdgcn_s_barrier();
        __builtin_amdgcn_sched_barrier(0);

        const short* Ac = As[cur];
        const short* Bc2 = Bs[cur];
        bf16x8 af[4], bfv[4];
        #pragma unroll
        for (int m = 0; m < 4; m++) {
            const int row = wm + m * 16 + lr;
            af[m] = *(const bf16x8*)&Ac[row * 32 + (lg ^ fread) * 8];
        }
        #pragma unroll
        for (int n = 0; n < 4; n++) {
            const int row = wn + n * 16 + lr;
            bfv[n] = *(const bf16x8*)&Bc2[row * 32 + (lg ^ fread) * 8];
        }
        #pragma unroll
        for (int m = 0; m < 4; m++)
            #pragma unroll
            for (int n = 0; n < 4; n++)
                acc[m][n] = mfma16(af[m], bfv[n], acc[m][n]);

        asm volatile("s_waitcnt lgkmcnt(0)" ::: "memory");
        __builtin_amdgcn_sched_barrier(0);
        __builtin_amdgcn_s_barrier();
        cur ^= 1;
    }
    asm volatile("s_waitcnt vmcnt(0)" ::: "memory");   // drain clamped extra stage

    if (g < 2) {
        unsigned short* Y = g == 0 ? Qo : Ko;
        #pragma unroll
        for (int n = 0; n < 4; n++) {
            const int col = tn * 128 + wn + n * 16 + lr;
            const float bv = bias[col];
            const int hh = col >> 6, hd = col & 63;
            #pragma unroll
            for (int m = 0; m < 4; m++) {
                const int row0 = tm * 128 + wm + m * 16 + lg * 4;
                const int b_ = row0 >> 11, sQ = row0 & 2047;
                #pragma unroll
                for (int r = 0; r < 4; r++) {
                    const float val = (acc[m][n][r] + bv) * scale;
                    Y[(((size_t)(b_ * Hc + hh)) * Sc + (sQ + r)) * HDc + hd] = f2bf(val);
                }
            }
        }
    } else {
        #pragma unroll
        for (int n = 0; n < 4; n++) {
            const int col = tn * 128 + wn + n * 16 + lr;
            const float bv = bias[col];
            const int hh = col >> 6, hd = col & 63;
            #pragma unroll
            for (int m = 0; m < 4; m++) {
                const int row0 = tm * 128 + wm + m * 16 + lg * 4;
                const int b_ = row0 >> 11, sQ = row0 & 2047;
                // swap bits 2<->3 of sQ: PV fragment permutation carried in memory
                const int sQp = (sQ & ~12) | ((sQ & 4) << 1) | ((sQ & 8) >> 1);
                unsigned long long pk = 0;
                #pragma unroll
                for (int r = 0; r < 4; r++)
                    pk |= (unsigned long long)f2bf(acc[m][n][r] + bv) << (16 * r);
                *(unsigned long long*)&Vto[(((size_t)(b_ * Hc + hh)) * HDc + hd) * Sc + sQp] = pk;
            }
        }
    }
}

// ---- output projection: dbuf + counted vmcnt ----
__global__ __launch_bounds__(256) void out_gemm(
    const unsigned short* __restrict__ Ab, const unsigned short* __restrict__ Bw,
    const float* __restrict__ bias, float* __restrict__ Y)
{
    __shared__ short As[2][4096];
    __shared__ short Bs[2][4096];
    const int tid = threadIdx.x, lane = tid & 63, w = tid >> 6;
    const int lr = lane & 15, lg = lane >> 4;
    const int tm = blockIdx.x & 31, tn = blockIdx.x >> 5;
    const int wm = (w >> 1) * 64, wn = (w & 1) * 64;

    const int c0 = 2 * w, c1 = 2 * w + 1;
    const int r0 = c0 * 16 + (lane >> 2), r1 = c1 * 16 + (lane >> 2);
    const int sl0 = ((lane & 3) ^ ((r0 >> 1) & 3)) * 8, sl1 = ((lane & 3) ^ ((r1 >> 1) & 3)) * 8;
    const unsigned short* Ap0 = Ab + (size_t)(tm * 128 + r0) * 1024 + sl0;
    const unsigned short* Ap1 = Ab + (size_t)(tm * 128 + r1) * 1024 + sl1;
    const unsigned short* Bp0 = Bw + (size_t)(tn * 128 + r0) * 1024 + sl0;
    const unsigned short* Bp1 = Bw + (size_t)(tn * 128 + r1) * 1024 + sl1;

    f32x4 acc[4][4] = {};
    const int fread = (lr >> 1) & 3;

    gload16(Ap0, &As[0][c0 * 512]);
    gload16(Ap1, &As[0][c1 * 512]);
    gload16(Bp0, &Bs[0][c0 * 512]);
    gload16(Bp1, &Bs[0][c1 * 512]);

    int cur = 0;
    for (int k0 = 0; k0 < 1024; k0 += 32) {
        const int nk = (k0 + 32 < 1024) ? k0 + 32 : k0;
        gload16(Ap0 + nk, &As[cur ^ 1][c0 * 512]);
        gload16(Ap1 + nk, &As[cur ^ 1][c1 * 512]);
        gload16(Bp0 + nk, &Bs[cur ^ 1][c0 * 512]);
        gload16(Bp1 + nk, &Bs[cur ^ 1][c1 * 512]);
        asm volatile("s_waitcnt vmcnt(4)" ::: "memory");
        __builtin_amdgcn_s_barrier();
        __builtin_amdgcn_sched_barrier(0);

        const short* Ac = As[cur];
        const short* Bc2 = Bs[cur];
        bf16x8 af[4], bfv[4];
        #pragma unroll
        for (int m = 0; m < 4; m++) {
            const int row = wm + m * 16 + lr;
            af[m] = *(const bf16x8*)&Ac[row * 32 + (lg ^ fread) * 8];
        }
        #pragma unroll
        for (int n = 0; n < 4; n++) {
            const int row = wn + n * 16 + lr;
            bfv[n] = *(const bf16x8*)&Bc2[row * 32 + (lg ^ fread) * 8];
        }
        #pragma unroll
        for (int m = 0; m < 4; m++)
            #pragma unroll
            for (int n = 0; n < 4; n++)
                acc[m][n] = mfma16(af[m], bfv[n], acc[m][n]);

        asm volatile("s_waitcnt lgkmcnt(0)" ::: "memory");
        __builtin_amdgcn_sched_barrier(0);
        __builtin_amdgcn_s_barrier();
        cur ^= 1;
    }
    asm volatile("s_waitcnt vmcnt(0)" ::: "memory");

    #pragma unroll
    for (int n = 0; n < 4; n++) {
        const int col = tn * 128 + wn + n * 16 + lr;
        const float bv = bias[col];
        #pragma unroll
        for (int m = 0; m < 4; m++) {
            const int row0 = tm * 128 + wm + m * 16 + lg * 4;
            #pragma unroll
            for (int r = 0; r < 4; r++)
                Y[(size_t)(row0 + r) * 1024 + col] = acc[m][n][r] + bv;
        }
    }
}

// ---- flash attention v10: 8 waves/block, 32x32x16 MFMA, in-lane P, V pre-permuted in
// global (k bits 2<->3 swapped per 16-group) so the PV B-fragment is one conflict-free
// b128 in the SAME k-order as the lane's own P pairs (MFMA k-convention cancels).
// accl ones-column MFMA for denominator; no-max exp2 softmax; XOR-swizzled LDS;
// counted-vmcnt(2) double buffer.
// Q,K: bf16 [B,H,S,HD] (Q pre-scaled by SCALE*log2e); V: bf16 [B,H,HD,S] permuted.
__global__ __launch_bounds__(512, 2) void attn_fwd(
    const unsigned short* __restrict__ Q, const unsigned short* __restrict__ Kg,
    const unsigned short* __restrict__ Vtg, unsigned short* __restrict__ ctx)
{
    __shared__ short Ks[2][4096];   // [buf][krow*64 + swz-slot]  (64 rows x 64 bf16)
    __shared__ short Vs[2][4096];   // [buf][hd*64  + swz-slot]   (k-permuted content)

    const int tid = threadIdx.x, lane = tid & 63, w = tid >> 6;   // w in 0..7
    const int l31 = lane & 31, hi = lane >> 5;

    // XCD-chunked: 256 blocks = 8 XCDs x 32; 4 heads per XCD, 8 q-tiles per head
    const int blk = blockIdx.x;
    const int idx = blk >> 3;
    const int bh = (blk & 7) * 4 + (idx >> 3);
    const int qt = idx & 7;

    const unsigned short* Qb = Q   + (size_t)bh * Sc * HDc;
    const unsigned short* Kb = Kg  + (size_t)bh * Sc * HDc;
    const unsigned short* Vb = Vtg + (size_t)bh * HDc * Sc;

    // Q B-frags: lane (col=q=l31, hi) holds Q[q][hd = 16*kk + 8*hi + e]
    const int qbase = qt * 256 + w * 32;
    bf16x8 qf[4];
    {
        const size_t qr = (size_t)(qbase + l31) * HDc + hi * 8;
        #pragma unroll
        for (int kk = 0; kk < 4; kk++)
            qf[kk] = *(const bf16x8*)&Qb[qr + kk * 16];
    }

    // staging: wave w stages 8 K rows + 8 V rows (64 lanes x 16B = 8 rows x 128B);
    // global source pre-swizzled so linear LDS dest holds slot' = slot ^ (row&7)
    const int srow  = w * 8 + (lane >> 3);
    const int sslot = ((lane & 7) ^ (lane >> 3)) * 8;
    const unsigned short* Kst = Kb + (size_t)srow * HDc + sslot;
    const unsigned short* Vst = Vb + (size_t)srow * Sc + sslot;

    const int swk = lane & 7;   // row&7 for all fragment rows this lane touches

    const f32x16 Z = {};
    f32x16 acc0 = {}, acc1 = {}, accl = {};   // ctx hd-tiles 0/1 + denominator l

    union { unsigned int u[4]; bf16x8 v; } ones;
    ones.u[0] = ones.u[1] = ones.u[2] = ones.u[3] = 0x3F803F80u;  // bf16 1.0 x8

    // prologue: stage tile 0 into buf 0 (1 K-gload + 1 V-gload per lane)
    gload16(Kst, &Ks[0][w * 512]);
    gload16(Vst, &Vs[0][w * 512]);

    int cur = 0;
    for (int kt = 0; kt < 32; ++kt) {
        {   // stage next tile (clamped re-stage on last iter keeps vmcnt uniform)
            const int nxt = kt < 31 ? kt + 1 : 31;
            gload16(Kst + (size_t)nxt * 4096, &Ks[cur ^ 1][w * 512]);
            gload16(Vst + nxt * 64,           &Vs[cur ^ 1][w * 512]);
        }
        asm volatile("s_waitcnt vmcnt(2)" ::: "memory");   // current tile's 2 done
        __builtin_amdgcn_s_barrier();
        __builtin_amdgcn_sched_barrier(0);

        const short* Kc = Ks[cur];
        const short* Vc = Vs[cur];

        // S^T = K·Q^T via 32x32x16: D col = q = l31, rows = k (regs).
        f32x16 sf0, sf1;
        __builtin_amdgcn_s_setprio(1);
        {
            const int sl = (hi ^ swk) * 8;
            bf16x8 a0 = *(const bf16x8*)&Kc[l31 * 64 + sl];
            bf16x8 a1 = *(const bf16x8*)&Kc[(32 + l31) * 64 + sl];
            sf0 = mfma32(a0, qf[0], Z);
            sf1 = mfma32(a1, qf[0], Z);
        }
        #pragma unroll
        for (int kk = 1; kk < 4; kk++) {
            const int sl = ((2 * kk + hi) ^ swk) * 8;
            bf16x8 a0 = *(const bf16x8*)&Kc[l31 * 64 + sl];
            bf16x8 a1 = *(const bf16x8*)&Kc[(32 + l31) * 64 + sl];
            sf0 = mfma32(a0, qf[kk], sf0);
            sf1 = mfma32(a1, qf[kk], sf1);
        }
        __builtin_amdgcn_s_setprio(0);

        // no-max softmax: P = exp2(s~). C/D reg r -> k = (r&3) + 8*(r>>2) + 4*hi
        // pair j packs regs (2j, 2j+1): j0:(k0,k1) j1:(k2,k3) j2:(k8,k9) j3:(k10,k11)
        // j4:(k16,k17) j5:(k18,k19) j6:(k24,k25) j7:(k26,k27)   (all +4hi; p1 = +32)
        unsigned int p0[8], p1[8];
        #pragma unroll
        for (int j = 0; j < 8; j++) {
            const float a0 = __builtin_amdgcn_exp2f(sf0[2 * j]);
            const float a1 = __builtin_amdgcn_exp2f(sf0[2 * j + 1]);
            const float b0 = __builtin_amdgcn_exp2f(sf1[2 * j]);
            const float b1 = __builtin_amdgcn_exp2f(sf1[2 * j + 1]);
            asm("v_cvt_pk_bf16_f32 %0, %1, %2" : "=v"(p0[j]) : "v"(a0), "v"(a1));
            asm("v_cvt_pk_bf16_f32 %0, %1, %2" : "=v"(p1[j]) : "v"(b0), "v"(b1));
        }

        // PV over 4 k-windows m (k in [16m,16m+16)). A-frag = lane's own 4 pairs:
        // element (hi,e) -> k = 16m + 4*hi + (e&3) + 8*(e>>2). B-frag: one b128 at
        // slot (2m+hi)^swk — the global k-permutation places exactly those k there.
        // accl accumulates the window row-sum l via B = ones.
        __builtin_amdgcn_s_setprio(1);
        #pragma unroll
        for (int m = 0; m < 4; m++) {
            const unsigned int* pw = (m < 2) ? &p0[(m & 1) * 4] : &p1[(m & 1) * 4];
            union { unsigned int u[4]; bf16x8 v; } af;
            af.u[0] = pw[0]; af.u[1] = pw[1]; af.u[2] = pw[2]; af.u[3] = pw[3];
            const int sl = ((2 * m + hi) ^ swk) * 8;
            bf16x8 b0 = *(const bf16x8*)&Vc[l31 * 64 + sl];
            bf16x8 b1 = *(const bf16x8*)&Vc[(32 + l31) * 64 + sl];
            acc0 = mfma32(af.v, b0, acc0);
            acc1 = mfma32(af.v, b1, acc1);
            accl = mfma32(af.v, ones.v, accl);
        }
        __builtin_amdgcn_s_setprio(0);

        asm volatile("s_waitcnt lgkmcnt(0)" ::: "memory");
        __builtin_amdgcn_sched_barrier(0);
        __builtin_amdgcn_s_barrier();
        cur ^= 1;
    }
    asm volatile("s_waitcnt vmcnt(0)" ::: "memory");

    // epilogue: lane holds l(q) in accl[r] (all cols equal); rcp + store
    const int b_ = bh >> 4, hh = bh & 15;
    #pragma unroll
    for (int r = 0; r < 16; r++) {
        const int qr = (r & 3) + 8 * (r >> 2) + 4 * hi;
        const float lv = __builtin_amdgcn_rcpf(accl[r]);
        const int sq = qbase + qr;
        unsigned short* co = &ctx[((size_t)(b_ * Sc + sq)) * Dc + (size_t)hh * HDc + l31];
        co[0]  = f2bf(acc0[r] * lv);
        co[32] = f2bf(acc1[r] * lv);
    }
}

extern "C" void kernel_launch(void* const* d_in, const int* in_sizes, int n_in,
                              void* d_out, int out_size, void* d_ws, size_t ws_size,
                              hipStream_t stream)
{
    const float* query = (const float*)d_in[0];
    const float* key   = (const float*)d_in[1];
    const float* value = (const float*)d_in[2];
    const float* Wq = (const float*)d_in[3];
    const float* bq = (const float*)d_in[4];
    const float* Wk = (const float*)d_in[5];
    const float* bk = (const float*)d_in[6];
    const float* Wv = (const float*)d_in[7];
    const float* bv = (const float*)d_in[8];
    const float* Wo = (const float*)d_in[9];
    const float* bo = (const float*)d_in[10];

    constexpr size_t W = 1048576, AE = 4194304;
    unsigned short* wqb = (unsigned short*)d_ws;
    unsigned short* wkb = wqb + W;
    unsigned short* wvb = wkb + W;
    unsigned short* wob = wvb + W;
    unsigned short* qb  = wob + W;
    unsigned short* kb  = qb + AE;
    unsigned short* vb  = kb + AE;
    unsigned short* Qh  = vb + AE;
    unsigned short* Kh  = Qh + AE;
    unsigned short* Vth = Kh + AE;
    unsigned short* cx  = qb;           // overlay: qb dead after qkv_gemm

    cvt_all<<<8192, 256, 0, stream>>>(query, key, value, Wq, Wk, Wv, Wo,
                                      qb, kb, vb, wqb, wkb, wvb, wob);
    qkv_gemm<<<768, 256, 0, stream>>>(qb, kb, vb, wqb, wkb, wvb,
                                      bq, bk, bv, Qh, Kh, Vth);
    attn_fwd<<<256, 512, 0, stream>>>(Qh, Kh, Vth, cx);
    out_gemm<<<256, 256, 0, stream>>>(cx, wob, bo, (float*)d_out);
}